// Round 7
// baseline (622.985 us; speedup 1.0000x reference)
//
#include <hip/hip_runtime.h>
#include <hip/hip_bf16.h>

#define N_NODES 100000
#define N_EDGES 1600000
#define N_GRAPHS 250
#define SCAN_CHUNK 512
#define NCHUNKS ((N_NODES + SCAN_CHUNK - 1) / SCAN_CHUNK)  // 196

__device__ __forceinline__ void atomAddF(float* p, float v) {
  unsafeAtomicAdd(p, v);  // hardware global_atomic_add_f32
}

__device__ __forceinline__ float4 add4(float4 a, float4 b) {
  return make_float4(a.x + b.x, a.y + b.y, a.z + b.z, a.w + b.w);
}

// Build x0 [N,16]: [node_h(9) | xg[batch](4) | 0,0,0]
__global__ void concat_kernel(const float* __restrict__ nh, const float* __restrict__ xg,
                              const int* __restrict__ batch, float* __restrict__ x0) {
  int idx = blockIdx.x * blockDim.x + threadIdx.x;
  if (idx >= N_NODES * 16) return;
  int n = idx >> 4, j = idx & 15;
  float v;
  if (j < 9)       v = nh[n * 9 + j];
  else if (j < 13) v = xg[batch[n] * 4 + (j - 9)];
  else             v = 0.0f;
  x0[idx] = v;
}

// ---- CSR build: histogram -> hierarchical scan -> scatter (int atomics only) ----
// x4 unroll: 4 independent atomic chains per thread (latency-bound kernel)
__global__ void hist_kernel(const int* __restrict__ dst, int* __restrict__ deg) {
  int e = (blockIdx.x * blockDim.x + threadIdx.x) * 4;
  if (e + 4 <= N_EDGES) {
    int4 d4 = *(const int4*)(dst + e);
    atomicAdd(&deg[d4.x], 1);
    atomicAdd(&deg[d4.y], 1);
    atomicAdd(&deg[d4.z], 1);
    atomicAdd(&deg[d4.w], 1);
  } else {
    for (; e < N_EDGES; ++e) atomicAdd(&deg[dst[e]], 1);
  }
}

// A: per-chunk partial sums (196 blocks x 256 threads, 2 elems/thread)
__global__ __launch_bounds__(256) void partial_kernel(const int* __restrict__ deg,
                                                      int* __restrict__ partial) {
  int b = blockIdx.x, t = threadIdx.x;
  int i0 = b * SCAN_CHUNK + t * 2;
  int s = 0;
  if (i0 < N_NODES) s += deg[i0];
  if (i0 + 1 < N_NODES) s += deg[i0 + 1];
  for (int off = 1; off < 64; off <<= 1) s += __shfl_xor(s, off);
  __shared__ int wsum[4];
  if ((t & 63) == 0) wsum[t >> 6] = s;
  __syncthreads();
  if (t == 0) partial[b] = wsum[0] + wsum[1] + wsum[2] + wsum[3];
}

// B: scan the 196 chunk partials (1 tiny block)
__global__ __launch_bounds__(256) void chunkscan_kernel(const int* __restrict__ partial,
                                                        int* __restrict__ chunkoff,
                                                        int* __restrict__ rowptr) {
  __shared__ int sh[256];
  int t = threadIdx.x;
  int v = (t < NCHUNKS) ? partial[t] : 0;
  sh[t] = v;
  __syncthreads();
  for (int off = 1; off < 256; off <<= 1) {  // Hillis-Steele inclusive
    int u = (t >= off) ? sh[t - off] : 0;
    __syncthreads();
    sh[t] += u;
    __syncthreads();
  }
  if (t < NCHUNKS) chunkoff[t] = sh[t] - v;  // exclusive prefix
  if (t == 0) rowptr[N_NODES] = N_EDGES;
}

// C: in-chunk scan + chunk offset -> rowptr/cursor; also emits inv = 1/max(deg,1)
__global__ __launch_bounds__(256) void rowptr_kernel(const int* __restrict__ deg,
                                                     const int* __restrict__ chunkoff,
                                                     int* __restrict__ rowptr,
                                                     int* __restrict__ cursor,
                                                     float* __restrict__ inv) {
  int b = blockIdx.x, t = threadIdx.x;
  int lane = t & 63, w = t >> 6;
  int i0 = b * SCAN_CHUNK + t * 2;
  int d0 = (i0 < N_NODES) ? deg[i0] : 0;
  int d1 = (i0 + 1 < N_NODES) ? deg[i0 + 1] : 0;
  int ps = d0 + d1;
  int v = ps;
  for (int off = 1; off < 64; off <<= 1) {  // wave-inclusive scan
    int u = __shfl_up(v, off);
    if (lane >= off) v += u;
  }
  __shared__ int wtot[4];
  if (lane == 63) wtot[w] = v;
  __syncthreads();
  int woff = 0;
  for (int i = 0; i < w; ++i) woff += wtot[i];
  int excl = chunkoff[b] + woff + v - ps;
  if (i0 < N_NODES) {
    rowptr[i0] = excl; cursor[i0] = excl;
    inv[i0] = 1.0f / fmaxf((float)d0, 1.0f);
  }
  if (i0 + 1 < N_NODES) {
    rowptr[i0 + 1] = excl + d0; cursor[i0 + 1] = excl + d0;
    inv[i0 + 1] = 1.0f / fmaxf((float)d1, 1.0f);
  }
}

// x4 unroll: 4 independent atomic->store chains per thread
__global__ void scatter_kernel(const int* __restrict__ src, const int* __restrict__ dst,
                               int* __restrict__ cursor, int* __restrict__ esorted) {
  int e = (blockIdx.x * blockDim.x + threadIdx.x) * 4;
  if (e + 4 <= N_EDGES) {
    int4 d4 = *(const int4*)(dst + e);
    int4 s4 = *(const int4*)(src + e);
    int p0 = atomicAdd(&cursor[d4.x], 1);
    int p1 = atomicAdd(&cursor[d4.y], 1);
    int p2 = atomicAdd(&cursor[d4.z], 1);
    int p3 = atomicAdd(&cursor[d4.w], 1);
    esorted[p0] = s4.x;
    esorted[p1] = s4.y;
    esorted[p2] = s4.z;
    esorted[p3] = s4.w;
  } else {
    for (; e < N_EDGES; ++e) {
      int pos = atomicAdd(&cursor[dst[e]], 1);
      esorted[pos] = src[e];
    }
  }
}

// ---- fused gather-mean-aggregate + SAGE transform ----
// block = 256 = 4 waves; tile = 16 nodes (4 per wave, 1 per quarter-wave).
// stage1: quarter-wave gathers its node's row set via float4 lanes (16 lanes x 16B = row),
//         edge loop unrolled x4 with independent accumulators -> 16 rows in flight/wave.
// stage2: wave transforms its 4 nodes together; W in LDS (transposed, conflict-free fill),
//         as/xs rows read as LDS broadcasts (conflict-free at any stride).
// ST=64 (no pad) for F=64: LDS = 40960 B exactly -> 4 blocks/CU (160 KiB budget).
template <int F, bool RELU>
__launch_bounds__(256)
__global__ void sage_fused(const float* __restrict__ x, const int* __restrict__ rowptr,
                           const int* __restrict__ esorted, const float* __restrict__ inv,
                           const float* __restrict__ Wl, const float* __restrict__ bl,
                           const float* __restrict__ Wr, int Fw, float* __restrict__ out) {
  constexpr int ST = (F == 64) ? 64 : 20;
  __shared__ float Wlt[F * 64];
  __shared__ float Wrt[F * 64];
  __shared__ float asld[16 * ST];
  __shared__ float xsld[16 * ST];
  for (int i = threadIdx.x; i < 64 * F; i += 256) {
    int h = i & 63, f = i >> 6;  // consecutive lanes -> consecutive LDS words (no conflict)
    Wlt[f * 64 + h] = (f < Fw) ? Wl[h * Fw + f] : 0.0f;
    Wrt[f * 64 + h] = (f < Fw) ? Wr[h * Fw + f] : 0.0f;
  }
  __syncthreads();
  const int lane = threadIdx.x & 63;
  const int w = threadIdx.x >> 6;
  const int q = lane >> 4;   // quarter-wave id: node within wave
  const int c = lane & 15;   // float4 column
  const float blv = bl[lane];
  const float4* xf4 = (const float4*)x;
  const int ntiles = N_NODES / 16;  // 6250
  for (int tile = blockIdx.x; tile < ntiles; tile += gridDim.x) {
    const int n = tile * 16 + w * 4 + q;
    const int e0 = rowptr[n], e1 = rowptr[n + 1];
    const float invn = inv[n];
    if (F == 64) {
      float4 a0 = {0, 0, 0, 0}, a1 = a0, a2 = a0, a3 = a0;
      int e = e0;
      for (; e + 4 <= e1; e += 4) {
        int s0 = esorted[e], s1 = esorted[e + 1], s2 = esorted[e + 2], s3 = esorted[e + 3];
        a0 = add4(a0, xf4[(size_t)s0 * 16 + c]);
        a1 = add4(a1, xf4[(size_t)s1 * 16 + c]);
        a2 = add4(a2, xf4[(size_t)s2 * 16 + c]);
        a3 = add4(a3, xf4[(size_t)s3 * 16 + c]);
      }
      for (; e < e1; ++e) a0 = add4(a0, xf4[(size_t)esorted[e] * 16 + c]);
      a0 = add4(add4(a0, a1), add4(a2, a3));
      float4 xv = xf4[(size_t)n * 16 + c];
      a0.x *= invn; a0.y *= invn; a0.z *= invn; a0.w *= invn;
      *(float4*)&asld[(w * 4 + q) * ST + 4 * c] = a0;
      *(float4*)&xsld[(w * 4 + q) * ST + 4 * c] = xv;
    } else {  // F == 16: 4 edge-subgroups x 4 float4-lanes per row
      const int eg = c >> 2, cc = c & 3;
      float4 a0 = {0, 0, 0, 0};
      for (int e = e0 + eg; e < e1; e += 4)
        a0 = add4(a0, xf4[(size_t)esorted[e] * 4 + cc]);
      a0.x += __shfl_xor(a0.x, 4); a0.y += __shfl_xor(a0.y, 4);
      a0.z += __shfl_xor(a0.z, 4); a0.w += __shfl_xor(a0.w, 4);
      a0.x += __shfl_xor(a0.x, 8); a0.y += __shfl_xor(a0.y, 8);
      a0.z += __shfl_xor(a0.z, 8); a0.w += __shfl_xor(a0.w, 8);
      if (eg == 0) {
        float4 xv = xf4[(size_t)n * 4 + cc];
        a0.x *= invn; a0.y *= invn; a0.z *= invn; a0.w *= invn;
        *(float4*)&asld[(w * 4 + q) * ST + 4 * cc] = a0;
        *(float4*)&xsld[(w * 4 + q) * ST + 4 * cc] = xv;
      }
    }
    // wave-local LDS produce->consume (wave w only touches rows w*4..w*4+3)
    __builtin_amdgcn_wave_barrier();
    const float* ar0 = &asld[(w * 4 + 0) * ST];
    const float* ar1 = &asld[(w * 4 + 1) * ST];
    const float* ar2 = &asld[(w * 4 + 2) * ST];
    const float* ar3 = &asld[(w * 4 + 3) * ST];
    const float* xr0 = &xsld[(w * 4 + 0) * ST];
    const float* xr1 = &xsld[(w * 4 + 1) * ST];
    const float* xr2 = &xsld[(w * 4 + 2) * ST];
    const float* xr3 = &xsld[(w * 4 + 3) * ST];
    float o0 = blv, o1 = blv, o2 = blv, o3 = blv;
#pragma unroll
    for (int f = 0; f < F; ++f) {
      float wl = Wlt[f * 64 + lane];
      float wr = Wrt[f * 64 + lane];
      o0 = fmaf(ar0[f], wl, fmaf(xr0[f], wr, o0));
      o1 = fmaf(ar1[f], wl, fmaf(xr1[f], wr, o1));
      o2 = fmaf(ar2[f], wl, fmaf(xr2[f], wr, o2));
      o3 = fmaf(ar3[f], wl, fmaf(xr3[f], wr, o3));
    }
    if (RELU) {
      o0 = fmaxf(o0, 0.0f); o1 = fmaxf(o1, 0.0f);
      o2 = fmaxf(o2, 0.0f); o3 = fmaxf(o3, 0.0f);
    }
    const size_t nb = (size_t)(tile * 16 + w * 4) * 64;
    out[nb + lane]       = o0;
    out[nb + 64 + lane]  = o1;
    out[nb + 128 + lane] = o2;
    out[nb + 192 + lane] = o3;
    __builtin_amdgcn_wave_barrier();
  }
}

// scatter-mean pooling: batch_idx sorted -> run-detection, one atomic per run per wave
__global__ void pool_kernel(const float* __restrict__ x, const int* __restrict__ batch,
                            float* __restrict__ pooled, float* __restrict__ cnt) {
  int wave = (blockIdx.x * blockDim.x + threadIdx.x) >> 6;
  int lane = threadIdx.x & 63;
  int n0 = wave * 64;
  if (n0 >= N_NODES) return;
  int nend = n0 + 64 < N_NODES ? n0 + 64 : N_NODES;
  int cur = -1;
  float acc = 0.0f, run = 0.0f;
  for (int n = n0; n < nend; ++n) {
    int b = batch[n];  // wave-uniform
    float v = x[(size_t)n * 64 + lane];
    if (b != cur) {
      if (cur >= 0) {
        atomAddF(&pooled[cur * 64 + lane], acc);
        if (lane == 0) atomAddF(&cnt[cur], run);
      }
      cur = b; acc = v; run = 1.0f;
    } else {
      acc += v; run += 1.0f;
    }
  }
  if (cur >= 0) {
    atomAddF(&pooled[cur * 64 + lane], acc);
    if (lane == 0) atomAddF(&cnt[cur], run);
  }
}

// per-graph MLP 64->64->64->64->1; one 64-thread block per graph
__global__ void mlp_kernel(const float* __restrict__ pooled, const float* __restrict__ cnt,
                           const float* __restrict__ W0, const float* __restrict__ b0,
                           const float* __restrict__ W1, const float* __restrict__ b1,
                           const float* __restrict__ W2, const float* __restrict__ b2,
                           const float* __restrict__ W3, const float* __restrict__ b3,
                           float* __restrict__ out) {
  int g = blockIdx.x, t = threadIdx.x;
  __shared__ float buf[2][64];
  float ic = 1.0f / fmaxf(cnt[g], 1.0f);
  buf[0][t] = pooled[g * 64 + t] * ic;
  __syncthreads();
  const float* Ws[3] = {W0, W1, W2};
  const float* Bs[3] = {b0, b1, b2};
  int cur = 0;
  for (int L = 0; L < 3; ++L) {
    const float* W = Ws[L];
    float acc = Bs[L][t];
#pragma unroll
    for (int f = 0; f < 64; ++f) acc = fmaf(W[t * 64 + f], buf[cur][f], acc);
    buf[cur ^ 1][t] = fmaxf(acc, 0.0f);
    __syncthreads();
    cur ^= 1;
  }
  float v = W3[t] * buf[cur][t];
  for (int off = 32; off; off >>= 1) v += __shfl_down(v, off);
  if (t == 0) out[g] = v + b3[0];
}

extern "C" void kernel_launch(void* const* d_in, const int* in_sizes, int n_in,
                              void* d_out, int out_size, void* d_ws, size_t ws_size,
                              hipStream_t stream) {
  const float* nh    = (const float*)d_in[0];
  const float* xg    = (const float*)d_in[1];
  const int*   ei    = (const int*)d_in[2];
  const int*   batch = (const int*)d_in[3];
  const float* s0Wl  = (const float*)d_in[4];
  const float* s0bl  = (const float*)d_in[5];
  const float* s0Wr  = (const float*)d_in[6];
  const float* s1Wl  = (const float*)d_in[7];
  const float* s1bl  = (const float*)d_in[8];
  const float* s1Wr  = (const float*)d_in[9];
  const float* s2Wl  = (const float*)d_in[10];
  const float* s2bl  = (const float*)d_in[11];
  const float* s2Wr  = (const float*)d_in[12];
  const float* mW0   = (const float*)d_in[13];
  const float* mb0   = (const float*)d_in[14];
  const float* mW1   = (const float*)d_in[15];
  const float* mb1   = (const float*)d_in[16];
  const float* mW2   = (const float*)d_in[17];
  const float* mb2   = (const float*)d_in[18];
  const float* mW3   = (const float*)d_in[19];
  const float* mb3   = (const float*)d_in[20];

  const int* src = ei;
  const int* dst = ei + N_EDGES;

  // ws layout
  float* B0     = (float*)d_ws;                     // N*64
  float* B1     = B0 + (size_t)N_NODES * 64;        // N*64
  float* inv    = B1 + (size_t)N_NODES * 64;        // N
  float* pooled = inv + N_NODES;                    // 250*64
  float* cnt    = pooled + (size_t)N_GRAPHS * 64;   // 250
  int*   deg     = (int*)(cnt + N_GRAPHS);          // N
  int*   rowptr  = deg + N_NODES;                   // N+1
  int*   cursor  = rowptr + (N_NODES + 1);          // N
  int*   esorted = cursor + N_NODES;                // E
  int*   partial  = esorted + N_EDGES;              // 256
  int*   chunkoff = partial + 256;                  // 256

  hipMemsetAsync(deg, 0, N_NODES * sizeof(int), stream);
  hipMemsetAsync(pooled, 0, (N_GRAPHS * 64 + N_GRAPHS) * sizeof(float), stream);

  // CSR build (hierarchical scan)
  hist_kernel<<<(N_EDGES / 4 + 255) / 256, 256, 0, stream>>>(dst, deg);
  partial_kernel<<<NCHUNKS, 256, 0, stream>>>(deg, partial);
  chunkscan_kernel<<<1, 256, 0, stream>>>(partial, chunkoff, rowptr);
  rowptr_kernel<<<NCHUNKS, 256, 0, stream>>>(deg, chunkoff, rowptr, cursor, inv);
  scatter_kernel<<<(N_EDGES / 4 + 255) / 256, 256, 0, stream>>>(src, dst, cursor, esorted);

  // x0 (stride 16) into B0
  concat_kernel<<<(N_NODES * 16 + 255) / 256, 256, 0, stream>>>(nh, xg, batch, B0);

  // fused layers: B0 -> B1 -> B0 -> B1
  sage_fused<16, true><<<2048, 256, 0, stream>>>(B0, rowptr, esorted, inv, s0Wl, s0bl, s0Wr, 13, B1);
  sage_fused<64, true><<<1024, 256, 0, stream>>>(B1, rowptr, esorted, inv, s1Wl, s1bl, s1Wr, 64, B0);
  sage_fused<64, false><<<1024, 256, 0, stream>>>(B0, rowptr, esorted, inv, s2Wl, s2bl, s2Wr, 64, B1);

  // pooling + MLP
  pool_kernel<<<((N_NODES + 63) / 64 * 64 + 255) / 256, 256, 0, stream>>>(B1, batch, pooled, cnt);
  mlp_kernel<<<N_GRAPHS, 64, 0, stream>>>(pooled, cnt, mW0, mb0, mW1, mb1, mW2, mb2, mW3, mb3,
                                          (float*)d_out);
}

// Round 8
// 455.905 us; speedup vs baseline: 1.3665x; 1.3665x over previous
//
#include <hip/hip_runtime.h>
#include <hip/hip_bf16.h>

#define N_NODES 100000
#define N_EDGES 1600000
#define N_GRAPHS 250
#define NB 391          // buckets of 256 nodes: bucket = dst >> 8
#define BCAP 6144       // bucket capacity (mean 4092, sigma ~64 -> 32-sigma margin)
#define BIN_BLOCKS 250
#define EPB 6400        // edges per bin block (25 per thread)

__device__ __forceinline__ void atomAddF(float* p, float v) {
  unsafeAtomicAdd(p, v);  // hardware global_atomic_add_f32
}

__device__ __forceinline__ float4 add4(float4 a, float4 b) {
  return make_float4(a.x + b.x, a.y + b.y, a.z + b.z, a.w + b.w);
}

// Build x0 [N,16]: [node_h(9) | xg[batch](4) | 0,0,0]
__global__ void concat_kernel(const float* __restrict__ nh, const float* __restrict__ xg,
                              const int* __restrict__ batch, float* __restrict__ x0) {
  int idx = blockIdx.x * blockDim.x + threadIdx.x;
  if (idx >= N_NODES * 16) return;
  int n = idx >> 4, j = idx & 15;
  float v;
  if (j < 9)       v = nh[n * 9 + j];
  else if (j < 13) v = xg[batch[n] * 4 + (j - 9)];
  else             v = 0.0f;
  x0[idx] = v;
}

// ---- CSR build via 2-level counting sort (XCD-local writes, no fp write amplification) ----

// Level 1: bin edges by dst>>8. Each block owns a contiguous run per bucket ->
// 64B-granular single-XCD writes. Payload packed (dstoff<<17 | src), 25 bits.
__global__ __launch_bounds__(256) void bin_kernel(const int* __restrict__ src,
                                                  const int* __restrict__ dst,
                                                  int* __restrict__ gcnt,
                                                  int* __restrict__ binned) {
  __shared__ int hist[NB];
  __shared__ int base[NB];
  const int t = threadIdx.x;
  for (int i = t; i < NB; i += 256) hist[i] = 0;
  __syncthreads();
  const int e0 = blockIdx.x * EPB;
  int d[25];
#pragma unroll
  for (int k = 0; k < 25; ++k) {
    d[k] = dst[e0 + k * 256 + t];
    atomicAdd(&hist[d[k] >> 8], 1);
  }
  __syncthreads();
  for (int i = t; i < NB; i += 256) {
    base[i] = atomicAdd(&gcnt[i], hist[i]);  // reserve [base, base+hist) in bucket i
    hist[i] = 0;                             // reuse as local cursor
  }
  __syncthreads();
#pragma unroll
  for (int k = 0; k < 25; ++k) {
    const int dd = d[k];
    const int b = dd >> 8;
    const int s = src[e0 + k * 256 + t];
    const int r = atomicAdd(&hist[b], 1);
    const int pos = base[b] + r;
    if (pos < BCAP) binned[b * BCAP + pos] = ((dd & 255) << 17) | s;
  }
}

// Level 1.5: exclusive scan of 391 bucket totals (1 block)
__global__ __launch_bounds__(512) void bucketscan_kernel(const int* __restrict__ gcnt,
                                                         int* __restrict__ bbase,
                                                         int* __restrict__ rowptr) {
  __shared__ int sh[512];
  int t = threadIdx.x;
  int v = (t < NB) ? gcnt[t] : 0;
  sh[t] = v;
  __syncthreads();
  for (int off = 1; off < 512; off <<= 1) {
    int u = (t >= off) ? sh[t - off] : 0;
    __syncthreads();
    sh[t] += u;
    __syncthreads();
  }
  if (t < NB) bbase[t] = sh[t] - v;  // exclusive prefix
  if (t == 0) rowptr[N_NODES] = N_EDGES;
}

// Level 2: per-bucket counting sort. All esorted writes land in the bucket's
// contiguous window (single block -> single XCD). Also emits rowptr + inv.
__global__ __launch_bounds__(256) void sort_kernel(const int* __restrict__ gcnt,
                                                   const int* __restrict__ bbase,
                                                   const int* __restrict__ binned,
                                                   int* __restrict__ esorted,
                                                   int* __restrict__ rowptr,
                                                   float* __restrict__ inv) {
  __shared__ int cnt[256];
  __shared__ int cur[256];
  __shared__ int sh[256];
  const int b = blockIdx.x, t = threadIdx.x;
  const int count = min(gcnt[b], BCAP);
  const int ebase = bbase[b];
  const int* __restrict__ bin = binned + b * BCAP;
  cnt[t] = 0;
  __syncthreads();
  for (int i = t; i < count; i += 256) atomicAdd(&cnt[bin[i] >> 17], 1);
  __syncthreads();
  const int c = cnt[t];
  sh[t] = c;
  __syncthreads();
  for (int off = 1; off < 256; off <<= 1) {  // Hillis-Steele inclusive
    int u = (t >= off) ? sh[t - off] : 0;
    __syncthreads();
    sh[t] += u;
    __syncthreads();
  }
  const int p = sh[t] - c;  // exclusive prefix within bucket
  cur[t] = p;
  const int node = b * 256 + t;
  if (node < N_NODES) {
    rowptr[node] = ebase + p;
    inv[node] = 1.0f / fmaxf((float)c, 1.0f);
  }
  __syncthreads();
  for (int i = t; i < count; i += 256) {
    const int v = bin[i];
    const int r = atomicAdd(&cur[v >> 17], 1);
    esorted[ebase + r] = v & 0x1FFFF;
  }
}

// ---- fused gather-mean-aggregate + SAGE transform ----
// block = 256 = 4 waves; tile = 16 nodes (4 per wave, 1 per quarter-wave).
// stage1: quarter-wave gathers its node's rows via float4 lanes (16 lanes x 16B = row),
//         edge loop unrolled x4 -> 16 rows in flight per wave.
// stage2: wave transforms its 4 nodes together; W transposed in LDS (conflict-free),
//         as/xs rows read as LDS broadcasts.
// ST=64 (no pad) for F=64: LDS = 40960 B exactly -> 4 blocks/CU.
template <int F, bool RELU>
__launch_bounds__(256)
__global__ void sage_fused(const float* __restrict__ x, const int* __restrict__ rowptr,
                           const int* __restrict__ esorted, const float* __restrict__ inv,
                           const float* __restrict__ Wl, const float* __restrict__ bl,
                           const float* __restrict__ Wr, int Fw, float* __restrict__ out) {
  constexpr int ST = (F == 64) ? 64 : 20;
  __shared__ float Wlt[F * 64];
  __shared__ float Wrt[F * 64];
  __shared__ float asld[16 * ST];
  __shared__ float xsld[16 * ST];
  for (int i = threadIdx.x; i < 64 * F; i += 256) {
    int h = i & 63, f = i >> 6;  // consecutive lanes -> consecutive LDS words (no conflict)
    Wlt[f * 64 + h] = (f < Fw) ? Wl[h * Fw + f] : 0.0f;
    Wrt[f * 64 + h] = (f < Fw) ? Wr[h * Fw + f] : 0.0f;
  }
  __syncthreads();
  const int lane = threadIdx.x & 63;
  const int w = threadIdx.x >> 6;
  const int q = lane >> 4;   // quarter-wave id: node within wave
  const int c = lane & 15;   // float4 column
  const float blv = bl[lane];
  const float4* xf4 = (const float4*)x;
  const int ntiles = N_NODES / 16;  // 6250
  for (int tile = blockIdx.x; tile < ntiles; tile += gridDim.x) {
    const int n = tile * 16 + w * 4 + q;
    const int e0 = rowptr[n], e1 = rowptr[n + 1];
    const float invn = inv[n];
    if (F == 64) {
      float4 a0 = {0, 0, 0, 0}, a1 = a0, a2 = a0, a3 = a0;
      int e = e0;
      for (; e + 4 <= e1; e += 4) {
        int s0 = esorted[e], s1 = esorted[e + 1], s2 = esorted[e + 2], s3 = esorted[e + 3];
        a0 = add4(a0, xf4[(size_t)s0 * 16 + c]);
        a1 = add4(a1, xf4[(size_t)s1 * 16 + c]);
        a2 = add4(a2, xf4[(size_t)s2 * 16 + c]);
        a3 = add4(a3, xf4[(size_t)s3 * 16 + c]);
      }
      for (; e < e1; ++e) a0 = add4(a0, xf4[(size_t)esorted[e] * 16 + c]);
      a0 = add4(add4(a0, a1), add4(a2, a3));
      float4 xv = xf4[(size_t)n * 16 + c];
      a0.x *= invn; a0.y *= invn; a0.z *= invn; a0.w *= invn;
      *(float4*)&asld[(w * 4 + q) * ST + 4 * c] = a0;
      *(float4*)&xsld[(w * 4 + q) * ST + 4 * c] = xv;
    } else {  // F == 16: 4 edge-subgroups x 4 float4-lanes per row
      const int eg = c >> 2, cc = c & 3;
      float4 a0 = {0, 0, 0, 0};
      for (int e = e0 + eg; e < e1; e += 4)
        a0 = add4(a0, xf4[(size_t)esorted[e] * 4 + cc]);
      a0.x += __shfl_xor(a0.x, 4); a0.y += __shfl_xor(a0.y, 4);
      a0.z += __shfl_xor(a0.z, 4); a0.w += __shfl_xor(a0.w, 4);
      a0.x += __shfl_xor(a0.x, 8); a0.y += __shfl_xor(a0.y, 8);
      a0.z += __shfl_xor(a0.z, 8); a0.w += __shfl_xor(a0.w, 8);
      if (eg == 0) {
        float4 xv = xf4[(size_t)n * 4 + cc];
        a0.x *= invn; a0.y *= invn; a0.z *= invn; a0.w *= invn;
        *(float4*)&asld[(w * 4 + q) * ST + 4 * cc] = a0;
        *(float4*)&xsld[(w * 4 + q) * ST + 4 * cc] = xv;
      }
    }
    // wave-local LDS produce->consume (wave w only touches rows w*4..w*4+3)
    __builtin_amdgcn_wave_barrier();
    const float* ar0 = &asld[(w * 4 + 0) * ST];
    const float* ar1 = &asld[(w * 4 + 1) * ST];
    const float* ar2 = &asld[(w * 4 + 2) * ST];
    const float* ar3 = &asld[(w * 4 + 3) * ST];
    const float* xr0 = &xsld[(w * 4 + 0) * ST];
    const float* xr1 = &xsld[(w * 4 + 1) * ST];
    const float* xr2 = &xsld[(w * 4 + 2) * ST];
    const float* xr3 = &xsld[(w * 4 + 3) * ST];
    float o0 = blv, o1 = blv, o2 = blv, o3 = blv;
#pragma unroll
    for (int f = 0; f < F; ++f) {
      float wl = Wlt[f * 64 + lane];
      float wr = Wrt[f * 64 + lane];
      o0 = fmaf(ar0[f], wl, fmaf(xr0[f], wr, o0));
      o1 = fmaf(ar1[f], wl, fmaf(xr1[f], wr, o1));
      o2 = fmaf(ar2[f], wl, fmaf(xr2[f], wr, o2));
      o3 = fmaf(ar3[f], wl, fmaf(xr3[f], wr, o3));
    }
    if (RELU) {
      o0 = fmaxf(o0, 0.0f); o1 = fmaxf(o1, 0.0f);
      o2 = fmaxf(o2, 0.0f); o3 = fmaxf(o3, 0.0f);
    }
    const size_t nb = (size_t)(tile * 16 + w * 4) * 64;
    out[nb + lane]       = o0;
    out[nb + 64 + lane]  = o1;
    out[nb + 128 + lane] = o2;
    out[nb + 192 + lane] = o3;
    __builtin_amdgcn_wave_barrier();
  }
}

// scatter-mean pooling: batch_idx sorted -> run-detection, one atomic per run per wave
__global__ void pool_kernel(const float* __restrict__ x, const int* __restrict__ batch,
                            float* __restrict__ pooled, float* __restrict__ cnt) {
  int wave = (blockIdx.x * blockDim.x + threadIdx.x) >> 6;
  int lane = threadIdx.x & 63;
  int n0 = wave * 64;
  if (n0 >= N_NODES) return;
  int nend = n0 + 64 < N_NODES ? n0 + 64 : N_NODES;
  int cur = -1;
  float acc = 0.0f, run = 0.0f;
  for (int n = n0; n < nend; ++n) {
    int b = batch[n];  // wave-uniform
    float v = x[(size_t)n * 64 + lane];
    if (b != cur) {
      if (cur >= 0) {
        atomAddF(&pooled[cur * 64 + lane], acc);
        if (lane == 0) atomAddF(&cnt[cur], run);
      }
      cur = b; acc = v; run = 1.0f;
    } else {
      acc += v; run += 1.0f;
    }
  }
  if (cur >= 0) {
    atomAddF(&pooled[cur * 64 + lane], acc);
    if (lane == 0) atomAddF(&cnt[cur], run);
  }
}

// per-graph MLP 64->64->64->64->1; one 64-thread block per graph
__global__ void mlp_kernel(const float* __restrict__ pooled, const float* __restrict__ cnt,
                           const float* __restrict__ W0, const float* __restrict__ b0,
                           const float* __restrict__ W1, const float* __restrict__ b1,
                           const float* __restrict__ W2, const float* __restrict__ b2,
                           const float* __restrict__ W3, const float* __restrict__ b3,
                           float* __restrict__ out) {
  int g = blockIdx.x, t = threadIdx.x;
  __shared__ float buf[2][64];
  float ic = 1.0f / fmaxf(cnt[g], 1.0f);
  buf[0][t] = pooled[g * 64 + t] * ic;
  __syncthreads();
  const float* Ws[3] = {W0, W1, W2};
  const float* Bs[3] = {b0, b1, b2};
  int cur = 0;
  for (int L = 0; L < 3; ++L) {
    const float* W = Ws[L];
    float acc = Bs[L][t];
#pragma unroll
    for (int f = 0; f < 64; ++f) acc = fmaf(W[t * 64 + f], buf[cur][f], acc);
    buf[cur ^ 1][t] = fmaxf(acc, 0.0f);
    __syncthreads();
    cur ^= 1;
  }
  float v = W3[t] * buf[cur][t];
  for (int off = 32; off; off >>= 1) v += __shfl_down(v, off);
  if (t == 0) out[g] = v + b3[0];
}

extern "C" void kernel_launch(void* const* d_in, const int* in_sizes, int n_in,
                              void* d_out, int out_size, void* d_ws, size_t ws_size,
                              hipStream_t stream) {
  const float* nh    = (const float*)d_in[0];
  const float* xg    = (const float*)d_in[1];
  const int*   ei    = (const int*)d_in[2];
  const int*   batch = (const int*)d_in[3];
  const float* s0Wl  = (const float*)d_in[4];
  const float* s0bl  = (const float*)d_in[5];
  const float* s0Wr  = (const float*)d_in[6];
  const float* s1Wl  = (const float*)d_in[7];
  const float* s1bl  = (const float*)d_in[8];
  const float* s1Wr  = (const float*)d_in[9];
  const float* s2Wl  = (const float*)d_in[10];
  const float* s2bl  = (const float*)d_in[11];
  const float* s2Wr  = (const float*)d_in[12];
  const float* mW0   = (const float*)d_in[13];
  const float* mb0   = (const float*)d_in[14];
  const float* mW1   = (const float*)d_in[15];
  const float* mb1   = (const float*)d_in[16];
  const float* mW2   = (const float*)d_in[17];
  const float* mb2   = (const float*)d_in[18];
  const float* mW3   = (const float*)d_in[19];
  const float* mb3   = (const float*)d_in[20];

  const int* src = ei;
  const int* dst = ei + N_EDGES;

  // ws layout
  float* B0     = (float*)d_ws;                     // N*64
  float* B1     = B0 + (size_t)N_NODES * 64;        // N*64
  float* inv    = B1 + (size_t)N_NODES * 64;        // N
  float* pooled = inv + N_NODES;                    // 250*64
  float* cnt    = pooled + (size_t)N_GRAPHS * 64;   // 250
  int*   rowptr  = (int*)(cnt + N_GRAPHS);          // N+1
  int*   esorted = rowptr + (N_NODES + 1);          // E
  int*   binned  = esorted + N_EDGES;               // NB*BCAP (~9.6 MB)
  int*   gcnt    = binned + (size_t)NB * BCAP;      // NB
  int*   bbase   = gcnt + NB;                       // NB

  hipMemsetAsync(gcnt, 0, NB * sizeof(int), stream);
  hipMemsetAsync(pooled, 0, (N_GRAPHS * 64 + N_GRAPHS) * sizeof(float), stream);

  // CSR build: 2-level counting sort
  bin_kernel<<<BIN_BLOCKS, 256, 0, stream>>>(src, dst, gcnt, binned);
  bucketscan_kernel<<<1, 512, 0, stream>>>(gcnt, bbase, rowptr);
  sort_kernel<<<NB, 256, 0, stream>>>(gcnt, bbase, binned, esorted, rowptr, inv);

  // x0 (stride 16) into B0
  concat_kernel<<<(N_NODES * 16 + 255) / 256, 256, 0, stream>>>(nh, xg, batch, B0);

  // fused layers: B0 -> B1 -> B0 -> B1
  sage_fused<16, true><<<2048, 256, 0, stream>>>(B0, rowptr, esorted, inv, s0Wl, s0bl, s0Wr, 13, B1);
  sage_fused<64, true><<<1024, 256, 0, stream>>>(B1, rowptr, esorted, inv, s1Wl, s1bl, s1Wr, 64, B0);
  sage_fused<64, false><<<1024, 256, 0, stream>>>(B0, rowptr, esorted, inv, s2Wl, s2bl, s2Wr, 64, B1);

  // pooling + MLP
  pool_kernel<<<((N_NODES + 63) / 64 * 64 + 255) / 256, 256, 0, stream>>>(B1, batch, pooled, cnt);
  mlp_kernel<<<N_GRAPHS, 64, 0, stream>>>(pooled, cnt, mW0, mb0, mW1, mb1, mW2, mb2, mW3, mb3,
                                          (float*)d_out);
}

// Round 9
// 425.294 us; speedup vs baseline: 1.4648x; 1.0720x over previous
//
#include <hip/hip_runtime.h>
#include <hip/hip_bf16.h>

#define N_NODES 100000
#define N_EDGES 1600000
#define N_GRAPHS 250
#define NB 391          // buckets of 256 nodes: bucket = dst >> 8
#define BCAP 6144       // bucket capacity (mean 4092, sigma ~64)
#define BIN_BLOCKS 250
#define EPB 6400        // edges per bin block (25 per thread)

typedef __hip_bfloat16 bf16;

__device__ __forceinline__ void atomAddF(float* p, float v) {
  unsafeAtomicAdd(p, v);
}

__device__ __forceinline__ float b2f(unsigned short u) {
  union { unsigned int i; float f; } v; v.i = ((unsigned)u) << 16; return v.f;
}

__device__ __forceinline__ void accb(float4& a, ushort4 u) {
  a.x += b2f(u.x); a.y += b2f(u.y); a.z += b2f(u.z); a.w += b2f(u.w);
}

__device__ __forceinline__ float4 add4(float4 a, float4 b) {
  return make_float4(a.x + b.x, a.y + b.y, a.z + b.z, a.w + b.w);
}

// Build x0 [N,16] fp32 + bf16 shadow: [node_h(9) | xg[batch](4) | 0,0,0]
__global__ void concat_kernel(const float* __restrict__ nh, const float* __restrict__ xg,
                              const int* __restrict__ batch, float* __restrict__ x0f,
                              bf16* __restrict__ x0b) {
  int idx = blockIdx.x * blockDim.x + threadIdx.x;
  if (idx >= N_NODES * 16) return;
  int n = idx >> 4, j = idx & 15;
  float v;
  if (j < 9)       v = nh[n * 9 + j];
  else if (j < 13) v = xg[batch[n] * 4 + (j - 9)];
  else             v = 0.0f;
  x0f[idx] = v;
  x0b[idx] = __float2bfloat16(v);
}

// ---- CSR build via 2-level counting sort ----
__global__ __launch_bounds__(256) void bin_kernel(const int* __restrict__ src,
                                                  const int* __restrict__ dst,
                                                  int* __restrict__ gcnt,
                                                  int* __restrict__ binned) {
  __shared__ int hist[NB];
  __shared__ int base[NB];
  const int t = threadIdx.x;
  for (int i = t; i < NB; i += 256) hist[i] = 0;
  __syncthreads();
  const int e0 = blockIdx.x * EPB;
  int d[25];
#pragma unroll
  for (int k = 0; k < 25; ++k) {
    d[k] = dst[e0 + k * 256 + t];
    atomicAdd(&hist[d[k] >> 8], 1);
  }
  __syncthreads();
  for (int i = t; i < NB; i += 256) {
    base[i] = atomicAdd(&gcnt[i], hist[i]);
    hist[i] = 0;
  }
  __syncthreads();
#pragma unroll
  for (int k = 0; k < 25; ++k) {
    const int dd = d[k];
    const int b = dd >> 8;
    const int s = src[e0 + k * 256 + t];
    const int r = atomicAdd(&hist[b], 1);
    const int pos = base[b] + r;
    if (pos < BCAP) binned[b * BCAP + pos] = ((dd & 255) << 17) | s;
  }
}

__global__ __launch_bounds__(512) void bucketscan_kernel(const int* __restrict__ gcnt,
                                                         int* __restrict__ bbase,
                                                         int* __restrict__ rowptr) {
  __shared__ int sh[512];
  int t = threadIdx.x;
  int v = (t < NB) ? gcnt[t] : 0;
  sh[t] = v;
  __syncthreads();
  for (int off = 1; off < 512; off <<= 1) {
    int u = (t >= off) ? sh[t - off] : 0;
    __syncthreads();
    sh[t] += u;
    __syncthreads();
  }
  if (t < NB) bbase[t] = sh[t] - v;
  if (t == 0) rowptr[N_NODES] = N_EDGES;
}

__global__ __launch_bounds__(256) void sort_kernel(const int* __restrict__ gcnt,
                                                   const int* __restrict__ bbase,
                                                   const int* __restrict__ binned,
                                                   int* __restrict__ esorted,
                                                   int* __restrict__ rowptr,
                                                   float* __restrict__ inv) {
  __shared__ int cnt[256];
  __shared__ int cur[256];
  __shared__ int sh[256];
  const int b = blockIdx.x, t = threadIdx.x;
  const int count = min(gcnt[b], BCAP);
  const int ebase = bbase[b];
  const int* __restrict__ bin = binned + b * BCAP;
  cnt[t] = 0;
  __syncthreads();
  for (int i = t; i < count; i += 256) atomicAdd(&cnt[bin[i] >> 17], 1);
  __syncthreads();
  const int c = cnt[t];
  sh[t] = c;
  __syncthreads();
  for (int off = 1; off < 256; off <<= 1) {
    int u = (t >= off) ? sh[t - off] : 0;
    __syncthreads();
    sh[t] += u;
    __syncthreads();
  }
  const int p = sh[t] - c;
  cur[t] = p;
  const int node = b * 256 + t;
  if (node < N_NODES) {
    rowptr[node] = ebase + p;
    inv[node] = 1.0f / fmaxf((float)c, 1.0f);
  }
  __syncthreads();
  for (int i = t; i < count; i += 256) {
    const int v = bin[i];
    const int r = atomicAdd(&cur[v >> 17], 1);
    esorted[ebase + r] = v & 0x1FFFF;
  }
}

// ---- fused gather-mean-aggregate + SAGE transform ----
// Gather reads the bf16 shadow (half traffic); self-term + all math fp32.
// block = 256 = 4 waves; tile = 16 nodes; quarter-wave per node; unroll 8.
template <int F, bool RELU, bool WB16>
__launch_bounds__(256)
__global__ void sage_fused(const float* __restrict__ xf, const bf16* __restrict__ xb,
                           const int* __restrict__ rowptr, const int* __restrict__ esorted,
                           const float* __restrict__ inv, const float* __restrict__ Wl,
                           const float* __restrict__ bl, const float* __restrict__ Wr,
                           int Fw, float* __restrict__ outf, bf16* __restrict__ outb) {
  constexpr int ST = (F == 64) ? 64 : 20;
  __shared__ float Wlt[F * 64];
  __shared__ float Wrt[F * 64];
  __shared__ float asld[16 * ST];
  __shared__ float xsld[16 * ST];
  for (int i = threadIdx.x; i < 64 * F; i += 256) {
    int h = i & 63, f = i >> 6;
    Wlt[f * 64 + h] = (f < Fw) ? Wl[h * Fw + f] : 0.0f;
    Wrt[f * 64 + h] = (f < Fw) ? Wr[h * Fw + f] : 0.0f;
  }
  __syncthreads();
  const int lane = threadIdx.x & 63;
  const int w = threadIdx.x >> 6;
  const int q = lane >> 4;
  const int c = lane & 15;
  const float blv = bl[lane];
  const float4* xf4 = (const float4*)xf;
  const ushort4* xbu = (const ushort4*)xb;  // 8B = 4 bf16 per unit
  const int ntiles = N_NODES / 16;
  for (int tile = blockIdx.x; tile < ntiles; tile += gridDim.x) {
    const int n = tile * 16 + w * 4 + q;
    const int e0 = rowptr[n], e1 = rowptr[n + 1];
    const float invn = inv[n];
    if (F == 64) {
      // row = 16 ushort4 units; lane c covers features 4c..4c+3
      float4 a0 = {0, 0, 0, 0}, a1 = a0, a2 = a0, a3 = a0;
      int e = e0;
      for (; e + 8 <= e1; e += 8) {
        int s0 = esorted[e], s1 = esorted[e + 1], s2 = esorted[e + 2], s3 = esorted[e + 3];
        int s4 = esorted[e + 4], s5 = esorted[e + 5], s6 = esorted[e + 6], s7 = esorted[e + 7];
        ushort4 u0 = xbu[(size_t)s0 * 16 + c];
        ushort4 u1 = xbu[(size_t)s1 * 16 + c];
        ushort4 u2 = xbu[(size_t)s2 * 16 + c];
        ushort4 u3 = xbu[(size_t)s3 * 16 + c];
        ushort4 u4 = xbu[(size_t)s4 * 16 + c];
        ushort4 u5 = xbu[(size_t)s5 * 16 + c];
        ushort4 u6 = xbu[(size_t)s6 * 16 + c];
        ushort4 u7 = xbu[(size_t)s7 * 16 + c];
        accb(a0, u0); accb(a1, u1); accb(a2, u2); accb(a3, u3);
        accb(a0, u4); accb(a1, u5); accb(a2, u6); accb(a3, u7);
      }
      for (; e + 4 <= e1; e += 4) {
        int s0 = esorted[e], s1 = esorted[e + 1], s2 = esorted[e + 2], s3 = esorted[e + 3];
        ushort4 u0 = xbu[(size_t)s0 * 16 + c];
        ushort4 u1 = xbu[(size_t)s1 * 16 + c];
        ushort4 u2 = xbu[(size_t)s2 * 16 + c];
        ushort4 u3 = xbu[(size_t)s3 * 16 + c];
        accb(a0, u0); accb(a1, u1); accb(a2, u2); accb(a3, u3);
      }
      for (; e < e1; ++e) accb(a0, xbu[(size_t)esorted[e] * 16 + c]);
      a0 = add4(add4(a0, a1), add4(a2, a3));
      float4 xv = xf4[(size_t)n * 16 + c];
      a0.x *= invn; a0.y *= invn; a0.z *= invn; a0.w *= invn;
      *(float4*)&asld[(w * 4 + q) * ST + 4 * c] = a0;
      *(float4*)&xsld[(w * 4 + q) * ST + 4 * c] = xv;
    } else {  // F == 16: row = 4 ushort4 units; 4 edge-subgroups x 4 lanes
      const int eg = c >> 2, cc = c & 3;
      float4 a0 = {0, 0, 0, 0}, a1 = a0;
      int e = e0 + eg;
      for (; e + 4 < e1; e += 8) {
        int sa = esorted[e], sb = esorted[e + 4];
        ushort4 ua = xbu[(size_t)sa * 4 + cc];
        ushort4 ub = xbu[(size_t)sb * 4 + cc];
        accb(a0, ua); accb(a1, ub);
      }
      if (e < e1) accb(a0, xbu[(size_t)esorted[e] * 4 + cc]);
      a0 = add4(a0, a1);
      a0.x += __shfl_xor(a0.x, 4); a0.y += __shfl_xor(a0.y, 4);
      a0.z += __shfl_xor(a0.z, 4); a0.w += __shfl_xor(a0.w, 4);
      a0.x += __shfl_xor(a0.x, 8); a0.y += __shfl_xor(a0.y, 8);
      a0.z += __shfl_xor(a0.z, 8); a0.w += __shfl_xor(a0.w, 8);
      if (eg == 0) {
        float4 xv = xf4[(size_t)n * 4 + cc];
        a0.x *= invn; a0.y *= invn; a0.z *= invn; a0.w *= invn;
        *(float4*)&asld[(w * 4 + q) * ST + 4 * cc] = a0;
        *(float4*)&xsld[(w * 4 + q) * ST + 4 * cc] = xv;
      }
    }
    __builtin_amdgcn_wave_barrier();
    const float* ar0 = &asld[(w * 4 + 0) * ST];
    const float* ar1 = &asld[(w * 4 + 1) * ST];
    const float* ar2 = &asld[(w * 4 + 2) * ST];
    const float* ar3 = &asld[(w * 4 + 3) * ST];
    const float* xr0 = &xsld[(w * 4 + 0) * ST];
    const float* xr1 = &xsld[(w * 4 + 1) * ST];
    const float* xr2 = &xsld[(w * 4 + 2) * ST];
    const float* xr3 = &xsld[(w * 4 + 3) * ST];
    float o0 = blv, o1 = blv, o2 = blv, o3 = blv;
#pragma unroll
    for (int f = 0; f < F; ++f) {
      float wl = Wlt[f * 64 + lane];
      float wr = Wrt[f * 64 + lane];
      o0 = fmaf(ar0[f], wl, fmaf(xr0[f], wr, o0));
      o1 = fmaf(ar1[f], wl, fmaf(xr1[f], wr, o1));
      o2 = fmaf(ar2[f], wl, fmaf(xr2[f], wr, o2));
      o3 = fmaf(ar3[f], wl, fmaf(xr3[f], wr, o3));
    }
    if (RELU) {
      o0 = fmaxf(o0, 0.0f); o1 = fmaxf(o1, 0.0f);
      o2 = fmaxf(o2, 0.0f); o3 = fmaxf(o3, 0.0f);
    }
    const size_t nb = (size_t)(tile * 16 + w * 4) * 64;
    outf[nb + lane]       = o0;
    outf[nb + 64 + lane]  = o1;
    outf[nb + 128 + lane] = o2;
    outf[nb + 192 + lane] = o3;
    if (WB16) {
      outb[nb + lane]       = __float2bfloat16(o0);
      outb[nb + 64 + lane]  = __float2bfloat16(o1);
      outb[nb + 128 + lane] = __float2bfloat16(o2);
      outb[nb + 192 + lane] = __float2bfloat16(o3);
    }
    __builtin_amdgcn_wave_barrier();
  }
}

// scatter-mean pooling: batch_idx sorted -> run-detection
__global__ void pool_kernel(const float* __restrict__ x, const int* __restrict__ batch,
                            float* __restrict__ pooled, float* __restrict__ cnt) {
  int wave = (blockIdx.x * blockDim.x + threadIdx.x) >> 6;
  int lane = threadIdx.x & 63;
  int n0 = wave * 64;
  if (n0 >= N_NODES) return;
  int nend = n0 + 64 < N_NODES ? n0 + 64 : N_NODES;
  int cur = -1;
  float acc = 0.0f, run = 0.0f;
  for (int n = n0; n < nend; ++n) {
    int b = batch[n];
    float v = x[(size_t)n * 64 + lane];
    if (b != cur) {
      if (cur >= 0) {
        atomAddF(&pooled[cur * 64 + lane], acc);
        if (lane == 0) atomAddF(&cnt[cur], run);
      }
      cur = b; acc = v; run = 1.0f;
    } else {
      acc += v; run += 1.0f;
    }
  }
  if (cur >= 0) {
    atomAddF(&pooled[cur * 64 + lane], acc);
    if (lane == 0) atomAddF(&cnt[cur], run);
  }
}

// per-graph MLP 64->64->64->64->1
__global__ void mlp_kernel(const float* __restrict__ pooled, const float* __restrict__ cnt,
                           const float* __restrict__ W0, const float* __restrict__ b0,
                           const float* __restrict__ W1, const float* __restrict__ b1,
                           const float* __restrict__ W2, const float* __restrict__ b2,
                           const float* __restrict__ W3, const float* __restrict__ b3,
                           float* __restrict__ out) {
  int g = blockIdx.x, t = threadIdx.x;
  __shared__ float buf[2][64];
  float ic = 1.0f / fmaxf(cnt[g], 1.0f);
  buf[0][t] = pooled[g * 64 + t] * ic;
  __syncthreads();
  const float* Ws[3] = {W0, W1, W2};
  const float* Bs[3] = {b0, b1, b2};
  int cur = 0;
  for (int L = 0; L < 3; ++L) {
    const float* W = Ws[L];
    float acc = Bs[L][t];
#pragma unroll
    for (int f = 0; f < 64; ++f) acc = fmaf(W[t * 64 + f], buf[cur][f], acc);
    buf[cur ^ 1][t] = fmaxf(acc, 0.0f);
    __syncthreads();
    cur ^= 1;
  }
  float v = W3[t] * buf[cur][t];
  for (int off = 32; off; off >>= 1) v += __shfl_down(v, off);
  if (t == 0) out[g] = v + b3[0];
}

extern "C" void kernel_launch(void* const* d_in, const int* in_sizes, int n_in,
                              void* d_out, int out_size, void* d_ws, size_t ws_size,
                              hipStream_t stream) {
  const float* nh    = (const float*)d_in[0];
  const float* xg    = (const float*)d_in[1];
  const int*   ei    = (const int*)d_in[2];
  const int*   batch = (const int*)d_in[3];
  const float* s0Wl  = (const float*)d_in[4];
  const float* s0bl  = (const float*)d_in[5];
  const float* s0Wr  = (const float*)d_in[6];
  const float* s1Wl  = (const float*)d_in[7];
  const float* s1bl  = (const float*)d_in[8];
  const float* s1Wr  = (const float*)d_in[9];
  const float* s2Wl  = (const float*)d_in[10];
  const float* s2bl  = (const float*)d_in[11];
  const float* s2Wr  = (const float*)d_in[12];
  const float* mW0   = (const float*)d_in[13];
  const float* mb0   = (const float*)d_in[14];
  const float* mW1   = (const float*)d_in[15];
  const float* mb1   = (const float*)d_in[16];
  const float* mW2   = (const float*)d_in[17];
  const float* mb2   = (const float*)d_in[18];
  const float* mW3   = (const float*)d_in[19];
  const float* mb3   = (const float*)d_in[20];

  const int* src = ei;
  const int* dst = ei + N_EDGES;

  // ws layout (float units; all region starts multiples of 4 floats = 16B)
  float* B0     = (float*)d_ws;                       // N*64 f32
  float* B1     = B0 + (size_t)N_NODES * 64;          // N*64 f32
  float* x0f    = B1 + (size_t)N_NODES * 64;          // N*16 f32
  float* inv    = x0f + (size_t)N_NODES * 16;         // N
  float* pooled = inv + N_NODES;                      // 250*64
  float* cnt    = pooled + (size_t)N_GRAPHS * 64;     // 250 (pad 256)
  int*   rowptr  = (int*)(cnt + 256);                 // N+1 (pad to 100004)
  int*   esorted = rowptr + 100004;                   // E
  bf16*  x0b     = (bf16*)(esorted + N_EDGES);        // N*16 bf16
  bf16*  B0b     = (bf16*)((float*)x0b + (size_t)N_NODES * 8);   // N*64 bf16
  bf16*  B1b     = (bf16*)((float*)B0b + (size_t)N_NODES * 32);  // N*64 bf16
  int*   binned  = (int*)B1b;                         // NB*BCAP ints (aliases B1b; done before L1)
  int*   gcnt    = (int*)((float*)B1b + (size_t)N_NODES * 32);   // NB (pad 400)
  int*   bbase   = gcnt + 400;                        // NB

  hipMemsetAsync(gcnt, 0, NB * sizeof(int), stream);
  hipMemsetAsync(pooled, 0, (N_GRAPHS * 64 + N_GRAPHS) * sizeof(float), stream);

  // CSR build: 2-level counting sort (binned lives in B1b's space, freed before L1 writes it)
  bin_kernel<<<BIN_BLOCKS, 256, 0, stream>>>(src, dst, gcnt, binned);
  bucketscan_kernel<<<1, 512, 0, stream>>>(gcnt, bbase, rowptr);
  sort_kernel<<<NB, 256, 0, stream>>>(gcnt, bbase, binned, esorted, rowptr, inv);

  // x0 fp32 + bf16 shadow
  concat_kernel<<<(N_NODES * 16 + 255) / 256, 256, 0, stream>>>(nh, xg, batch, x0f, x0b);

  // fused layers: x0 -> B0 -> B1 -> B0
  sage_fused<16, true, true><<<2048, 256, 0, stream>>>(x0f, x0b, rowptr, esorted, inv,
                                                       s0Wl, s0bl, s0Wr, 13, B0, B0b);
  sage_fused<64, true, true><<<2048, 256, 0, stream>>>(B0, B0b, rowptr, esorted, inv,
                                                       s1Wl, s1bl, s1Wr, 64, B1, B1b);
  sage_fused<64, false, false><<<2048, 256, 0, stream>>>(B1, B1b, rowptr, esorted, inv,
                                                         s2Wl, s2bl, s2Wr, 64, B0, nullptr);

  // pooling + MLP
  pool_kernel<<<((N_NODES + 63) / 64 * 64 + 255) / 256, 256, 0, stream>>>(B0, batch, pooled, cnt);
  mlp_kernel<<<N_GRAPHS, 64, 0, stream>>>(pooled, cnt, mW0, mb0, mW1, mb1, mW2, mb2, mW3, mb3,
                                          (float*)d_out);
}

// Round 10
// 406.357 us; speedup vs baseline: 1.5331x; 1.0466x over previous
//
#include <hip/hip_runtime.h>
#include <hip/hip_bf16.h>

#define N_NODES 100000
#define N_EDGES 1600000
#define N_GRAPHS 250
#define NB 391          // buckets of 256 nodes: bucket = dst >> 8
#define BCAP 6144       // bucket capacity (mean 4092, sigma ~64)
#define BIN_BLOCKS 250
#define EPB 6400        // edges per bin block (25 per thread)

typedef __hip_bfloat16 bf16;

__device__ __forceinline__ void atomAddF(float* p, float v) {
  unsafeAtomicAdd(p, v);
}

__device__ __forceinline__ float b2f(unsigned short u) {
  union { unsigned int i; float f; } v; v.i = ((unsigned)u) << 16; return v.f;
}

__device__ __forceinline__ void accb(float4& a, ushort4 u) {
  a.x += b2f(u.x); a.y += b2f(u.y); a.z += b2f(u.z); a.w += b2f(u.w);
}

__device__ __forceinline__ float4 add4(float4 a, float4 b) {
  return make_float4(a.x + b.x, a.y + b.y, a.z + b.z, a.w + b.w);
}

// Build x0 [N,16] fp32 + bf16 shadow: [node_h(9) | xg[batch](4) | 0,0,0]
__global__ void concat_kernel(const float* __restrict__ nh, const float* __restrict__ xg,
                              const int* __restrict__ batch, float* __restrict__ x0f,
                              bf16* __restrict__ x0b) {
  int idx = blockIdx.x * blockDim.x + threadIdx.x;
  if (idx >= N_NODES * 16) return;
  int n = idx >> 4, j = idx & 15;
  float v;
  if (j < 9)       v = nh[n * 9 + j];
  else if (j < 13) v = xg[batch[n] * 4 + (j - 9)];
  else             v = 0.0f;
  x0f[idx] = v;
  x0b[idx] = __float2bfloat16(v);
}

// ---- CSR build via 2-level counting sort ----
__global__ __launch_bounds__(256) void bin_kernel(const int* __restrict__ src,
                                                  const int* __restrict__ dst,
                                                  int* __restrict__ gcnt,
                                                  int* __restrict__ binned) {
  __shared__ int hist[NB];
  __shared__ int base[NB];
  const int t = threadIdx.x;
  for (int i = t; i < NB; i += 256) hist[i] = 0;
  __syncthreads();
  const int e0 = blockIdx.x * EPB;
  int d[25];
#pragma unroll
  for (int k = 0; k < 25; ++k) {
    d[k] = dst[e0 + k * 256 + t];
    atomicAdd(&hist[d[k] >> 8], 1);
  }
  __syncthreads();
  for (int i = t; i < NB; i += 256) {
    base[i] = atomicAdd(&gcnt[i], hist[i]);
    hist[i] = 0;
  }
  __syncthreads();
#pragma unroll
  for (int k = 0; k < 25; ++k) {
    const int dd = d[k];
    const int b = dd >> 8;
    const int s = src[e0 + k * 256 + t];
    const int r = atomicAdd(&hist[b], 1);
    const int pos = base[b] + r;
    if (pos < BCAP) binned[b * BCAP + pos] = ((dd & 255) << 17) | s;
  }
}

__global__ __launch_bounds__(512) void bucketscan_kernel(const int* __restrict__ gcnt,
                                                         int* __restrict__ bbase,
                                                         int* __restrict__ rowptr) {
  __shared__ int sh[512];
  int t = threadIdx.x;
  int v = (t < NB) ? gcnt[t] : 0;
  sh[t] = v;
  __syncthreads();
  for (int off = 1; off < 512; off <<= 1) {
    int u = (t >= off) ? sh[t - off] : 0;
    __syncthreads();
    sh[t] += u;
    __syncthreads();
  }
  if (t < NB) bbase[t] = sh[t] - v;
  if (t == 0) rowptr[N_NODES] = N_EDGES;
}

__global__ __launch_bounds__(256) void sort_kernel(const int* __restrict__ gcnt,
                                                   const int* __restrict__ bbase,
                                                   const int* __restrict__ binned,
                                                   int* __restrict__ esorted,
                                                   int* __restrict__ rowptr,
                                                   float* __restrict__ inv) {
  __shared__ int cnt[256];
  __shared__ int cur[256];
  __shared__ int sh[256];
  const int b = blockIdx.x, t = threadIdx.x;
  const int count = min(gcnt[b], BCAP);
  const int ebase = bbase[b];
  const int* __restrict__ bin = binned + b * BCAP;
  cnt[t] = 0;
  __syncthreads();
  for (int i = t; i < count; i += 256) atomicAdd(&cnt[bin[i] >> 17], 1);
  __syncthreads();
  const int c = cnt[t];
  sh[t] = c;
  __syncthreads();
  for (int off = 1; off < 256; off <<= 1) {
    int u = (t >= off) ? sh[t - off] : 0;
    __syncthreads();
    sh[t] += u;
    __syncthreads();
  }
  const int p = sh[t] - c;
  cur[t] = p;
  const int node = b * 256 + t;
  if (node < N_NODES) {
    rowptr[node] = ebase + p;
    inv[node] = 1.0f / fmaxf((float)c, 1.0f);
  }
  __syncthreads();
  for (int i = t; i < count; i += 256) {
    const int v = bin[i];
    const int r = atomicAdd(&cur[v >> 17], 1);
    esorted[ebase + r] = v & 0x1FFFF;
  }
}

// ---- fused gather-mean-aggregate + SAGE transform ----
// 512 threads = 8 waves; tile = 32 nodes (4 per wave, 1 per quarter-wave).
// LDS(F=64) = 32KB W + 16KB staging = 48KB -> 3 blocks/CU = 24 waves/CU (75% cap),
// up from 16 waves (R9): more gathers in flight for the latency-bound random-read path.
template <int F, bool RELU, bool WB16>
__launch_bounds__(512)
__global__ void sage_fused(const float* __restrict__ xf, const bf16* __restrict__ xb,
                           const int* __restrict__ rowptr, const int* __restrict__ esorted,
                           const float* __restrict__ inv, const float* __restrict__ Wl,
                           const float* __restrict__ bl, const float* __restrict__ Wr,
                           int Fw, float* __restrict__ outf, bf16* __restrict__ outb) {
  constexpr int ST = (F == 64) ? 64 : 20;
  constexpr int NT = 32;  // nodes per tile
  __shared__ float Wlt[F * 64];
  __shared__ float Wrt[F * 64];
  __shared__ float asld[NT * ST];
  __shared__ float xsld[NT * ST];
  for (int i = threadIdx.x; i < 64 * F; i += 512) {
    int h = i & 63, f = i >> 6;
    Wlt[f * 64 + h] = (f < Fw) ? Wl[h * Fw + f] : 0.0f;
    Wrt[f * 64 + h] = (f < Fw) ? Wr[h * Fw + f] : 0.0f;
  }
  __syncthreads();
  const int lane = threadIdx.x & 63;
  const int w = threadIdx.x >> 6;   // 0..7
  const int q = lane >> 4;
  const int c = lane & 15;
  const int slot = w * 4 + q;       // 0..31
  const float blv = bl[lane];
  const float4* xf4 = (const float4*)xf;
  const ushort4* xbu = (const ushort4*)xb;
  const int ntiles = N_NODES / NT;  // 3125
  for (int tile = blockIdx.x; tile < ntiles; tile += gridDim.x) {
    const int n = tile * NT + slot;
    const int e0 = rowptr[n], e1 = rowptr[n + 1];
    const float invn = inv[n];
    if (F == 64) {
      float4 a0 = {0, 0, 0, 0}, a1 = a0, a2 = a0, a3 = a0;
      int e = e0;
      for (; e + 8 <= e1; e += 8) {
        int s0 = esorted[e], s1 = esorted[e + 1], s2 = esorted[e + 2], s3 = esorted[e + 3];
        int s4 = esorted[e + 4], s5 = esorted[e + 5], s6 = esorted[e + 6], s7 = esorted[e + 7];
        ushort4 u0 = xbu[(size_t)s0 * 16 + c];
        ushort4 u1 = xbu[(size_t)s1 * 16 + c];
        ushort4 u2 = xbu[(size_t)s2 * 16 + c];
        ushort4 u3 = xbu[(size_t)s3 * 16 + c];
        ushort4 u4 = xbu[(size_t)s4 * 16 + c];
        ushort4 u5 = xbu[(size_t)s5 * 16 + c];
        ushort4 u6 = xbu[(size_t)s6 * 16 + c];
        ushort4 u7 = xbu[(size_t)s7 * 16 + c];
        accb(a0, u0); accb(a1, u1); accb(a2, u2); accb(a3, u3);
        accb(a0, u4); accb(a1, u5); accb(a2, u6); accb(a3, u7);
      }
      for (; e + 4 <= e1; e += 4) {
        int s0 = esorted[e], s1 = esorted[e + 1], s2 = esorted[e + 2], s3 = esorted[e + 3];
        ushort4 u0 = xbu[(size_t)s0 * 16 + c];
        ushort4 u1 = xbu[(size_t)s1 * 16 + c];
        ushort4 u2 = xbu[(size_t)s2 * 16 + c];
        ushort4 u3 = xbu[(size_t)s3 * 16 + c];
        accb(a0, u0); accb(a1, u1); accb(a2, u2); accb(a3, u3);
      }
      for (; e < e1; ++e) accb(a0, xbu[(size_t)esorted[e] * 16 + c]);
      a0 = add4(add4(a0, a1), add4(a2, a3));
      float4 xv = xf4[(size_t)n * 16 + c];
      a0.x *= invn; a0.y *= invn; a0.z *= invn; a0.w *= invn;
      *(float4*)&asld[slot * ST + 4 * c] = a0;
      *(float4*)&xsld[slot * ST + 4 * c] = xv;
    } else {  // F == 16
      const int eg = c >> 2, cc = c & 3;
      float4 a0 = {0, 0, 0, 0}, a1 = a0;
      int e = e0 + eg;
      for (; e + 4 < e1; e += 8) {
        int sa = esorted[e], sb = esorted[e + 4];
        ushort4 ua = xbu[(size_t)sa * 4 + cc];
        ushort4 ub = xbu[(size_t)sb * 4 + cc];
        accb(a0, ua); accb(a1, ub);
      }
      if (e < e1) accb(a0, xbu[(size_t)esorted[e] * 4 + cc]);
      a0 = add4(a0, a1);
      a0.x += __shfl_xor(a0.x, 4); a0.y += __shfl_xor(a0.y, 4);
      a0.z += __shfl_xor(a0.z, 4); a0.w += __shfl_xor(a0.w, 4);
      a0.x += __shfl_xor(a0.x, 8); a0.y += __shfl_xor(a0.y, 8);
      a0.z += __shfl_xor(a0.z, 8); a0.w += __shfl_xor(a0.w, 8);
      if (eg == 0) {
        float4 xv = xf4[(size_t)n * 4 + cc];
        a0.x *= invn; a0.y *= invn; a0.z *= invn; a0.w *= invn;
        *(float4*)&asld[slot * ST + 4 * cc] = a0;
        *(float4*)&xsld[slot * ST + 4 * cc] = xv;
      }
    }
    // wave-local LDS produce->consume (wave w only touches slots w*4..w*4+3)
    __builtin_amdgcn_wave_barrier();
    const float* ar0 = &asld[(w * 4 + 0) * ST];
    const float* ar1 = &asld[(w * 4 + 1) * ST];
    const float* ar2 = &asld[(w * 4 + 2) * ST];
    const float* ar3 = &asld[(w * 4 + 3) * ST];
    const float* xr0 = &xsld[(w * 4 + 0) * ST];
    const float* xr1 = &xsld[(w * 4 + 1) * ST];
    const float* xr2 = &xsld[(w * 4 + 2) * ST];
    const float* xr3 = &xsld[(w * 4 + 3) * ST];
    float o0 = blv, o1 = blv, o2 = blv, o3 = blv;
#pragma unroll
    for (int f = 0; f < F; ++f) {
      float wl = Wlt[f * 64 + lane];
      float wr = Wrt[f * 64 + lane];
      o0 = fmaf(ar0[f], wl, fmaf(xr0[f], wr, o0));
      o1 = fmaf(ar1[f], wl, fmaf(xr1[f], wr, o1));
      o2 = fmaf(ar2[f], wl, fmaf(xr2[f], wr, o2));
      o3 = fmaf(ar3[f], wl, fmaf(xr3[f], wr, o3));
    }
    if (RELU) {
      o0 = fmaxf(o0, 0.0f); o1 = fmaxf(o1, 0.0f);
      o2 = fmaxf(o2, 0.0f); o3 = fmaxf(o3, 0.0f);
    }
    const size_t nb = (size_t)(tile * NT + w * 4) * 64;
    outf[nb + lane]       = o0;
    outf[nb + 64 + lane]  = o1;
    outf[nb + 128 + lane] = o2;
    outf[nb + 192 + lane] = o3;
    if (WB16) {
      outb[nb + lane]       = __float2bfloat16(o0);
      outb[nb + 64 + lane]  = __float2bfloat16(o1);
      outb[nb + 128 + lane] = __float2bfloat16(o2);
      outb[nb + 192 + lane] = __float2bfloat16(o3);
    }
    __builtin_amdgcn_wave_barrier();
  }
}

// scatter-mean pooling: batch_idx sorted -> run-detection
__global__ void pool_kernel(const float* __restrict__ x, const int* __restrict__ batch,
                            float* __restrict__ pooled, float* __restrict__ cnt) {
  int wave = (blockIdx.x * blockDim.x + threadIdx.x) >> 6;
  int lane = threadIdx.x & 63;
  int n0 = wave * 64;
  if (n0 >= N_NODES) return;
  int nend = n0 + 64 < N_NODES ? n0 + 64 : N_NODES;
  int cur = -1;
  float acc = 0.0f, run = 0.0f;
  for (int n = n0; n < nend; ++n) {
    int b = batch[n];
    float v = x[(size_t)n * 64 + lane];
    if (b != cur) {
      if (cur >= 0) {
        atomAddF(&pooled[cur * 64 + lane], acc);
        if (lane == 0) atomAddF(&cnt[cur], run);
      }
      cur = b; acc = v; run = 1.0f;
    } else {
      acc += v; run += 1.0f;
    }
  }
  if (cur >= 0) {
    atomAddF(&pooled[cur * 64 + lane], acc);
    if (lane == 0) atomAddF(&cnt[cur], run);
  }
}

// per-graph MLP 64->64->64->64->1
__global__ void mlp_kernel(const float* __restrict__ pooled, const float* __restrict__ cnt,
                           const float* __restrict__ W0, const float* __restrict__ b0,
                           const float* __restrict__ W1, const float* __restrict__ b1,
                           const float* __restrict__ W2, const float* __restrict__ b2,
                           const float* __restrict__ W3, const float* __restrict__ b3,
                           float* __restrict__ out) {
  int g = blockIdx.x, t = threadIdx.x;
  __shared__ float buf[2][64];
  float ic = 1.0f / fmaxf(cnt[g], 1.0f);
  buf[0][t] = pooled[g * 64 + t] * ic;
  __syncthreads();
  const float* Ws[3] = {W0, W1, W2};
  const float* Bs[3] = {b0, b1, b2};
  int cur = 0;
  for (int L = 0; L < 3; ++L) {
    const float* W = Ws[L];
    float acc = Bs[L][t];
#pragma unroll
    for (int f = 0; f < 64; ++f) acc = fmaf(W[t * 64 + f], buf[cur][f], acc);
    buf[cur ^ 1][t] = fmaxf(acc, 0.0f);
    __syncthreads();
    cur ^= 1;
  }
  float v = W3[t] * buf[cur][t];
  for (int off = 32; off; off >>= 1) v += __shfl_down(v, off);
  if (t == 0) out[g] = v + b3[0];
}

extern "C" void kernel_launch(void* const* d_in, const int* in_sizes, int n_in,
                              void* d_out, int out_size, void* d_ws, size_t ws_size,
                              hipStream_t stream) {
  const float* nh    = (const float*)d_in[0];
  const float* xg    = (const float*)d_in[1];
  const int*   ei    = (const int*)d_in[2];
  const int*   batch = (const int*)d_in[3];
  const float* s0Wl  = (const float*)d_in[4];
  const float* s0bl  = (const float*)d_in[5];
  const float* s0Wr  = (const float*)d_in[6];
  const float* s1Wl  = (const float*)d_in[7];
  const float* s1bl  = (const float*)d_in[8];
  const float* s1Wr  = (const float*)d_in[9];
  const float* s2Wl  = (const float*)d_in[10];
  const float* s2bl  = (const float*)d_in[11];
  const float* s2Wr  = (const float*)d_in[12];
  const float* mW0   = (const float*)d_in[13];
  const float* mb0   = (const float*)d_in[14];
  const float* mW1   = (const float*)d_in[15];
  const float* mb1   = (const float*)d_in[16];
  const float* mW2   = (const float*)d_in[17];
  const float* mb2   = (const float*)d_in[18];
  const float* mW3   = (const float*)d_in[19];
  const float* mb3   = (const float*)d_in[20];

  const int* src = ei;
  const int* dst = ei + N_EDGES;

  // ws layout (float units; all region starts multiples of 4 floats = 16B)
  float* B0     = (float*)d_ws;                       // N*64 f32
  float* B1     = B0 + (size_t)N_NODES * 64;          // N*64 f32
  float* x0f    = B1 + (size_t)N_NODES * 64;          // N*16 f32
  float* inv    = x0f + (size_t)N_NODES * 16;         // N
  float* pooled = inv + N_NODES;                      // 250*64
  float* cnt    = pooled + (size_t)N_GRAPHS * 64;     // 250 (pad 256)
  int*   rowptr  = (int*)(cnt + 256);                 // N+1 (pad to 100004)
  int*   esorted = rowptr + 100004;                   // E
  bf16*  x0b     = (bf16*)(esorted + N_EDGES);        // N*16 bf16
  bf16*  B0b     = (bf16*)((float*)x0b + (size_t)N_NODES * 8);   // N*64 bf16
  bf16*  B1b     = (bf16*)((float*)B0b + (size_t)N_NODES * 32);  // N*64 bf16
  int*   binned  = (int*)B1b;                         // NB*BCAP ints (aliases B1b; done before L1)
  int*   gcnt    = (int*)((float*)B1b + (size_t)N_NODES * 32);   // NB (pad 400)
  int*   bbase   = gcnt + 400;                        // NB

  hipMemsetAsync(gcnt, 0, NB * sizeof(int), stream);
  hipMemsetAsync(pooled, 0, (N_GRAPHS * 64 + N_GRAPHS) * sizeof(float), stream);

  // CSR build: 2-level counting sort (binned lives in B1b's space, freed before L1 writes it)
  bin_kernel<<<BIN_BLOCKS, 256, 0, stream>>>(src, dst, gcnt, binned);
  bucketscan_kernel<<<1, 512, 0, stream>>>(gcnt, bbase, rowptr);
  sort_kernel<<<NB, 256, 0, stream>>>(gcnt, bbase, binned, esorted, rowptr, inv);

  // x0 fp32 + bf16 shadow
  concat_kernel<<<(N_NODES * 16 + 255) / 256, 256, 0, stream>>>(nh, xg, batch, x0f, x0b);

  // fused layers: x0 -> B0 -> B1 -> B0
  sage_fused<16, true, true><<<1024, 512, 0, stream>>>(x0f, x0b, rowptr, esorted, inv,
                                                       s0Wl, s0bl, s0Wr, 13, B0, B0b);
  sage_fused<64, true, true><<<768, 512, 0, stream>>>(B0, B0b, rowptr, esorted, inv,
                                                      s1Wl, s1bl, s1Wr, 64, B1, B1b);
  sage_fused<64, false, false><<<768, 512, 0, stream>>>(B1, B1b, rowptr, esorted, inv,
                                                        s2Wl, s2bl, s2Wr, 64, B0, nullptr);

  // pooling + MLP
  pool_kernel<<<((N_NODES + 63) / 64 * 64 + 255) / 256, 256, 0, stream>>>(B0, batch, pooled, cnt);
  mlp_kernel<<<N_GRAPHS, 64, 0, stream>>>(pooled, cnt, mW0, mb0, mW1, mb1, mW2, mb2, mW3, mb3,
                                          (float*)d_out);
}

// Round 11
// 383.564 us; speedup vs baseline: 1.6242x; 1.0594x over previous
//
#include <hip/hip_runtime.h>
#include <hip/hip_bf16.h>

#define N_NODES 100000
#define N_EDGES 1600000
#define N_GRAPHS 250
#define NB 391          // buckets of 256 nodes: bucket = dst >> 8
#define BCAP 6144       // bucket capacity (mean 4092, sigma ~64)
#define BIN_BLOCKS 250
#define EPB 6400        // edges per bin block (25 per thread)

typedef __hip_bfloat16 bf16;

__device__ __forceinline__ void atomAddF(float* p, float v) {
  unsafeAtomicAdd(p, v);
}

__device__ __forceinline__ float b2f(unsigned short u) {
  union { unsigned int i; float f; } v; v.i = ((unsigned)u) << 16; return v.f;
}

__device__ __forceinline__ void accb(float4& a, ushort4 u) {
  a.x += b2f(u.x); a.y += b2f(u.y); a.z += b2f(u.z); a.w += b2f(u.w);
}

__device__ __forceinline__ float4 b2f4(ushort4 u) {
  return make_float4(b2f(u.x), b2f(u.y), b2f(u.z), b2f(u.w));
}

__device__ __forceinline__ float4 add4(float4 a, float4 b) {
  return make_float4(a.x + b.x, a.y + b.y, a.z + b.z, a.w + b.w);
}

// Build x0 [N,16] bf16: [node_h(9) | xg[batch](4) | 0,0,0]
__global__ void concat_kernel(const float* __restrict__ nh, const float* __restrict__ xg,
                              const int* __restrict__ batch, bf16* __restrict__ x0b) {
  int idx = blockIdx.x * blockDim.x + threadIdx.x;
  if (idx >= N_NODES * 16) return;
  int n = idx >> 4, j = idx & 15;
  float v;
  if (j < 9)       v = nh[n * 9 + j];
  else if (j < 13) v = xg[batch[n] * 4 + (j - 9)];
  else             v = 0.0f;
  x0b[idx] = __float2bfloat16(v);
}

// ---- CSR build via 2-level counting sort ----
__global__ __launch_bounds__(256) void bin_kernel(const int* __restrict__ src,
                                                  const int* __restrict__ dst,
                                                  int* __restrict__ gcnt,
                                                  int* __restrict__ binned) {
  __shared__ int hist[NB];
  __shared__ int base[NB];
  const int t = threadIdx.x;
  for (int i = t; i < NB; i += 256) hist[i] = 0;
  __syncthreads();
  const int e0 = blockIdx.x * EPB;
  int d[25];
#pragma unroll
  for (int k = 0; k < 25; ++k) {
    d[k] = dst[e0 + k * 256 + t];
    atomicAdd(&hist[d[k] >> 8], 1);
  }
  __syncthreads();
  for (int i = t; i < NB; i += 256) {
    base[i] = atomicAdd(&gcnt[i], hist[i]);
    hist[i] = 0;
  }
  __syncthreads();
#pragma unroll
  for (int k = 0; k < 25; ++k) {
    const int dd = d[k];
    const int b = dd >> 8;
    const int s = src[e0 + k * 256 + t];
    const int r = atomicAdd(&hist[b], 1);
    const int pos = base[b] + r;
    if (pos < BCAP) binned[b * BCAP + pos] = ((dd & 255) << 17) | s;
  }
}

__global__ __launch_bounds__(512) void bucketscan_kernel(const int* __restrict__ gcnt,
                                                         int* __restrict__ bbase,
                                                         int* __restrict__ rowptr) {
  __shared__ int sh[512];
  int t = threadIdx.x;
  int v = (t < NB) ? gcnt[t] : 0;
  sh[t] = v;
  __syncthreads();
  for (int off = 1; off < 512; off <<= 1) {
    int u = (t >= off) ? sh[t - off] : 0;
    __syncthreads();
    sh[t] += u;
    __syncthreads();
  }
  if (t < NB) bbase[t] = sh[t] - v;
  if (t == 0) rowptr[N_NODES] = N_EDGES;
}

__global__ __launch_bounds__(256) void sort_kernel(const int* __restrict__ gcnt,
                                                   const int* __restrict__ bbase,
                                                   const int* __restrict__ binned,
                                                   int* __restrict__ esorted,
                                                   int* __restrict__ rowptr,
                                                   float* __restrict__ inv) {
  __shared__ int cnt[256];
  __shared__ int cur[256];
  __shared__ int sh[256];
  const int b = blockIdx.x, t = threadIdx.x;
  const int count = min(gcnt[b], BCAP);
  const int ebase = bbase[b];
  const int* __restrict__ bin = binned + b * BCAP;
  cnt[t] = 0;
  __syncthreads();
  for (int i = t; i < count; i += 256) atomicAdd(&cnt[bin[i] >> 17], 1);
  __syncthreads();
  const int c = cnt[t];
  sh[t] = c;
  __syncthreads();
  for (int off = 1; off < 256; off <<= 1) {
    int u = (t >= off) ? sh[t - off] : 0;
    __syncthreads();
    sh[t] += u;
    __syncthreads();
  }
  const int p = sh[t] - c;
  cur[t] = p;
  const int node = b * 256 + t;
  if (node < N_NODES) {
    rowptr[node] = ebase + p;
    inv[node] = 1.0f / fmaxf((float)c, 1.0f);
  }
  __syncthreads();
  for (int i = t; i < count; i += 256) {
    const int v = bin[i];
    const int r = atomicAdd(&cur[v >> 17], 1);
    esorted[ebase + r] = v & 0x1FFFF;
  }
}

// ---- fused gather-mean-aggregate + SAGE transform (bf16 activations, fp32 math) ----
// 512 threads = 8 waves; tile = 32 nodes (1 per quarter-wave).
// Self-term AND gather both read the bf16 activation array; inter-layer
// activations are bf16-only (last layer writes fp32 for pooling).
template <int F, bool RELU, bool OUTF32>
__launch_bounds__(512)
__global__ void sage_fused(const bf16* __restrict__ xb, const int* __restrict__ rowptr,
                           const int* __restrict__ esorted, const float* __restrict__ inv,
                           const float* __restrict__ Wl, const float* __restrict__ bl,
                           const float* __restrict__ Wr, int Fw,
                           float* __restrict__ outf, bf16* __restrict__ outb) {
  constexpr int ST = (F == 64) ? 64 : 20;
  constexpr int NT = 32;  // nodes per tile
  __shared__ float Wlt[F * 64];
  __shared__ float Wrt[F * 64];
  __shared__ float asld[NT * ST];
  __shared__ float xsld[NT * ST];
  for (int i = threadIdx.x; i < 64 * F; i += 512) {
    int h = i & 63, f = i >> 6;
    Wlt[f * 64 + h] = (f < Fw) ? Wl[h * Fw + f] : 0.0f;
    Wrt[f * 64 + h] = (f < Fw) ? Wr[h * Fw + f] : 0.0f;
  }
  __syncthreads();
  const int lane = threadIdx.x & 63;
  const int w = threadIdx.x >> 6;   // 0..7
  const int q = lane >> 4;
  const int c = lane & 15;
  const int slot = w * 4 + q;       // 0..31
  const float blv = bl[lane];
  const ushort4* xbu = (const ushort4*)xb;  // 8B = 4 bf16
  const int ntiles = N_NODES / NT;  // 3125
  for (int tile = blockIdx.x; tile < ntiles; tile += gridDim.x) {
    const int n = tile * NT + slot;
    const int e0 = rowptr[n], e1 = rowptr[n + 1];
    const float invn = inv[n];
    if (F == 64) {
      float4 a0 = {0, 0, 0, 0}, a1 = a0, a2 = a0, a3 = a0;
      int e = e0;
      for (; e + 8 <= e1; e += 8) {
        int s0 = esorted[e], s1 = esorted[e + 1], s2 = esorted[e + 2], s3 = esorted[e + 3];
        int s4 = esorted[e + 4], s5 = esorted[e + 5], s6 = esorted[e + 6], s7 = esorted[e + 7];
        ushort4 u0 = xbu[(size_t)s0 * 16 + c];
        ushort4 u1 = xbu[(size_t)s1 * 16 + c];
        ushort4 u2 = xbu[(size_t)s2 * 16 + c];
        ushort4 u3 = xbu[(size_t)s3 * 16 + c];
        ushort4 u4 = xbu[(size_t)s4 * 16 + c];
        ushort4 u5 = xbu[(size_t)s5 * 16 + c];
        ushort4 u6 = xbu[(size_t)s6 * 16 + c];
        ushort4 u7 = xbu[(size_t)s7 * 16 + c];
        accb(a0, u0); accb(a1, u1); accb(a2, u2); accb(a3, u3);
        accb(a0, u4); accb(a1, u5); accb(a2, u6); accb(a3, u7);
      }
      for (; e + 4 <= e1; e += 4) {
        int s0 = esorted[e], s1 = esorted[e + 1], s2 = esorted[e + 2], s3 = esorted[e + 3];
        ushort4 u0 = xbu[(size_t)s0 * 16 + c];
        ushort4 u1 = xbu[(size_t)s1 * 16 + c];
        ushort4 u2 = xbu[(size_t)s2 * 16 + c];
        ushort4 u3 = xbu[(size_t)s3 * 16 + c];
        accb(a0, u0); accb(a1, u1); accb(a2, u2); accb(a3, u3);
      }
      for (; e < e1; ++e) accb(a0, xbu[(size_t)esorted[e] * 16 + c]);
      a0 = add4(add4(a0, a1), add4(a2, a3));
      float4 xv = b2f4(xbu[(size_t)n * 16 + c]);  // self row (bf16, L2-warm)
      a0.x *= invn; a0.y *= invn; a0.z *= invn; a0.w *= invn;
      *(float4*)&asld[slot * ST + 4 * c] = a0;
      *(float4*)&xsld[slot * ST + 4 * c] = xv;
    } else {  // F == 16
      const int eg = c >> 2, cc = c & 3;
      float4 a0 = {0, 0, 0, 0}, a1 = a0;
      int e = e0 + eg;
      for (; e + 4 < e1; e += 8) {
        int sa = esorted[e], sb = esorted[e + 4];
        ushort4 ua = xbu[(size_t)sa * 4 + cc];
        ushort4 ub = xbu[(size_t)sb * 4 + cc];
        accb(a0, ua); accb(a1, ub);
      }
      if (e < e1) accb(a0, xbu[(size_t)esorted[e] * 4 + cc]);
      a0 = add4(a0, a1);
      a0.x += __shfl_xor(a0.x, 4); a0.y += __shfl_xor(a0.y, 4);
      a0.z += __shfl_xor(a0.z, 4); a0.w += __shfl_xor(a0.w, 4);
      a0.x += __shfl_xor(a0.x, 8); a0.y += __shfl_xor(a0.y, 8);
      a0.z += __shfl_xor(a0.z, 8); a0.w += __shfl_xor(a0.w, 8);
      if (eg == 0) {
        float4 xv = b2f4(xbu[(size_t)n * 4 + cc]);
        a0.x *= invn; a0.y *= invn; a0.z *= invn; a0.w *= invn;
        *(float4*)&asld[slot * ST + 4 * cc] = a0;
        *(float4*)&xsld[slot * ST + 4 * cc] = xv;
      }
    }
    // wave-local LDS produce->consume (wave w only touches slots w*4..w*4+3)
    __builtin_amdgcn_wave_barrier();
    const float* ar0 = &asld[(w * 4 + 0) * ST];
    const float* ar1 = &asld[(w * 4 + 1) * ST];
    const float* ar2 = &asld[(w * 4 + 2) * ST];
    const float* ar3 = &asld[(w * 4 + 3) * ST];
    const float* xr0 = &xsld[(w * 4 + 0) * ST];
    const float* xr1 = &xsld[(w * 4 + 1) * ST];
    const float* xr2 = &xsld[(w * 4 + 2) * ST];
    const float* xr3 = &xsld[(w * 4 + 3) * ST];
    float o0 = blv, o1 = blv, o2 = blv, o3 = blv;
#pragma unroll
    for (int f = 0; f < F; ++f) {
      float wl = Wlt[f * 64 + lane];
      float wr = Wrt[f * 64 + lane];
      o0 = fmaf(ar0[f], wl, fmaf(xr0[f], wr, o0));
      o1 = fmaf(ar1[f], wl, fmaf(xr1[f], wr, o1));
      o2 = fmaf(ar2[f], wl, fmaf(xr2[f], wr, o2));
      o3 = fmaf(ar3[f], wl, fmaf(xr3[f], wr, o3));
    }
    if (RELU) {
      o0 = fmaxf(o0, 0.0f); o1 = fmaxf(o1, 0.0f);
      o2 = fmaxf(o2, 0.0f); o3 = fmaxf(o3, 0.0f);
    }
    const size_t nb = (size_t)(tile * NT + w * 4) * 64;
    if (OUTF32) {
      outf[nb + lane]       = o0;
      outf[nb + 64 + lane]  = o1;
      outf[nb + 128 + lane] = o2;
      outf[nb + 192 + lane] = o3;
    } else {
      outb[nb + lane]       = __float2bfloat16(o0);
      outb[nb + 64 + lane]  = __float2bfloat16(o1);
      outb[nb + 128 + lane] = __float2bfloat16(o2);
      outb[nb + 192 + lane] = __float2bfloat16(o3);
    }
    __builtin_amdgcn_wave_barrier();
  }
}

// scatter-mean pooling: batch_idx sorted -> run-detection
__global__ void pool_kernel(const float* __restrict__ x, const int* __restrict__ batch,
                            float* __restrict__ pooled, float* __restrict__ cnt) {
  int wave = (blockIdx.x * blockDim.x + threadIdx.x) >> 6;
  int lane = threadIdx.x & 63;
  int n0 = wave * 64;
  if (n0 >= N_NODES) return;
  int nend = n0 + 64 < N_NODES ? n0 + 64 : N_NODES;
  int cur = -1;
  float acc = 0.0f, run = 0.0f;
  for (int n = n0; n < nend; ++n) {
    int b = batch[n];
    float v = x[(size_t)n * 64 + lane];
    if (b != cur) {
      if (cur >= 0) {
        atomAddF(&pooled[cur * 64 + lane], acc);
        if (lane == 0) atomAddF(&cnt[cur], run);
      }
      cur = b; acc = v; run = 1.0f;
    } else {
      acc += v; run += 1.0f;
    }
  }
  if (cur >= 0) {
    atomAddF(&pooled[cur * 64 + lane], acc);
    if (lane == 0) atomAddF(&cnt[cur], run);
  }
}

// per-graph MLP 64->64->64->64->1
__global__ void mlp_kernel(const float* __restrict__ pooled, const float* __restrict__ cnt,
                           const float* __restrict__ W0, const float* __restrict__ b0,
                           const float* __restrict__ W1, const float* __restrict__ b1,
                           const float* __restrict__ W2, const float* __restrict__ b2,
                           const float* __restrict__ W3, const float* __restrict__ b3,
                           float* __restrict__ out) {
  int g = blockIdx.x, t = threadIdx.x;
  __shared__ float buf[2][64];
  float ic = 1.0f / fmaxf(cnt[g], 1.0f);
  buf[0][t] = pooled[g * 64 + t] * ic;
  __syncthreads();
  const float* Ws[3] = {W0, W1, W2};
  const float* Bs[3] = {b0, b1, b2};
  int cur = 0;
  for (int L = 0; L < 3; ++L) {
    const float* W = Ws[L];
    float acc = Bs[L][t];
#pragma unroll
    for (int f = 0; f < 64; ++f) acc = fmaf(W[t * 64 + f], buf[cur][f], acc);
    buf[cur ^ 1][t] = fmaxf(acc, 0.0f);
    __syncthreads();
    cur ^= 1;
  }
  float v = W3[t] * buf[cur][t];
  for (int off = 32; off; off >>= 1) v += __shfl_down(v, off);
  if (t == 0) out[g] = v + b3[0];
}

extern "C" void kernel_launch(void* const* d_in, const int* in_sizes, int n_in,
                              void* d_out, int out_size, void* d_ws, size_t ws_size,
                              hipStream_t stream) {
  const float* nh    = (const float*)d_in[0];
  const float* xg    = (const float*)d_in[1];
  const int*   ei    = (const int*)d_in[2];
  const int*   batch = (const int*)d_in[3];
  const float* s0Wl  = (const float*)d_in[4];
  const float* s0bl  = (const float*)d_in[5];
  const float* s0Wr  = (const float*)d_in[6];
  const float* s1Wl  = (const float*)d_in[7];
  const float* s1bl  = (const float*)d_in[8];
  const float* s1Wr  = (const float*)d_in[9];
  const float* s2Wl  = (const float*)d_in[10];
  const float* s2bl  = (const float*)d_in[11];
  const float* s2Wr  = (const float*)d_in[12];
  const float* mW0   = (const float*)d_in[13];
  const float* mb0   = (const float*)d_in[14];
  const float* mW1   = (const float*)d_in[15];
  const float* mb1   = (const float*)d_in[16];
  const float* mW2   = (const float*)d_in[17];
  const float* mb2   = (const float*)d_in[18];
  const float* mW3   = (const float*)d_in[19];
  const float* mb3   = (const float*)d_in[20];

  const int* src = ei;
  const int* dst = ei + N_EDGES;

  // ws layout (float units; every region start is 16B-aligned)
  float* B0f    = (float*)d_ws;                       // N*64 f32 (final layer out, pooled input)
  bf16*  x0b    = (bf16*)(B0f + (size_t)N_NODES * 64);          // N*16 bf16 (= N*8 floats)
  bf16*  B0b    = (bf16*)((float*)x0b + (size_t)N_NODES * 8);   // N*64 bf16 (= N*32 floats)
  bf16*  B1b    = (bf16*)((float*)B0b + (size_t)N_NODES * 32);  // N*64 bf16 (= N*32 floats)
  float* inv    = (float*)B1b + (size_t)N_NODES * 32; // N
  float* pooled = inv + N_NODES;                      // 250*64
  float* cnt    = pooled + (size_t)N_GRAPHS * 64;     // 250 (pad 256)
  int*   rowptr  = (int*)(cnt + 256);                 // N+1 (pad 100004)
  int*   esorted = rowptr + 100004;                   // E
  int*   gcnt    = esorted + N_EDGES;                 // NB (pad 400)
  int*   bbase   = gcnt + 400;                        // NB (pad 400)
  int*   binned  = (int*)B1b;                         // NB*BCAP ints (9.6MB <= B1b's 12.8MB;
                                                      // consumed by sort before L1 writes B1b)

  hipMemsetAsync(gcnt, 0, NB * sizeof(int), stream);
  hipMemsetAsync(pooled, 0, (N_GRAPHS * 64 + N_GRAPHS) * sizeof(float), stream);

  // CSR build: 2-level counting sort
  bin_kernel<<<BIN_BLOCKS, 256, 0, stream>>>(src, dst, gcnt, binned);
  bucketscan_kernel<<<1, 512, 0, stream>>>(gcnt, bbase, rowptr);
  sort_kernel<<<NB, 256, 0, stream>>>(gcnt, bbase, binned, esorted, rowptr, inv);

  // x0 bf16
  concat_kernel<<<(N_NODES * 16 + 255) / 256, 256, 0, stream>>>(nh, xg, batch, x0b);

  // fused layers: x0b -> B0b -> B1b -> B0f
  sage_fused<16, true, false><<<1024, 512, 0, stream>>>(x0b, rowptr, esorted, inv,
                                                        s0Wl, s0bl, s0Wr, 13, nullptr, B0b);
  sage_fused<64, true, false><<<768, 512, 0, stream>>>(B0b, rowptr, esorted, inv,
                                                       s1Wl, s1bl, s1Wr, 64, nullptr, B1b);
  sage_fused<64, false, true><<<768, 512, 0, stream>>>(B1b, rowptr, esorted, inv,
                                                       s2Wl, s2bl, s2Wr, 64, B0f, nullptr);

  // pooling + MLP
  pool_kernel<<<((N_NODES + 63) / 64 * 64 + 255) / 256, 256, 0, stream>>>(B0f, batch, pooled, cnt);
  mlp_kernel<<<N_GRAPHS, 64, 0, stream>>>(pooled, cnt, mW0, mb0, mW1, mb1, mW2, mb2, mW3, mb3,
                                          (float*)d_out);
}

// Round 12
// 368.640 us; speedup vs baseline: 1.6900x; 1.0405x over previous
//
#include <hip/hip_runtime.h>
#include <hip/hip_bf16.h>

#define N_NODES 100000
#define N_EDGES 1600000
#define N_GRAPHS 250
#define NB 391          // buckets of 256 nodes: bucket = dst >> 8
#define BCAP 6144       // bucket capacity (mean 4092, sigma ~64)
#define BIN_BLOCKS 250
#define EPB 6400        // edges per bin block (25 per thread)

typedef __hip_bfloat16 bf16;

__device__ __forceinline__ void atomAddF(float* p, float v) {
  unsafeAtomicAdd(p, v);
}

__device__ __forceinline__ float b2f(unsigned short u) {
  union { unsigned int i; float f; } v; v.i = ((unsigned)u) << 16; return v.f;
}

__device__ __forceinline__ float asF(unsigned int i) {
  union { unsigned int i; float f; } v; v.i = i; return v.f;
}

__device__ __forceinline__ void accb(float4& a, ushort4 u) {
  a.x += b2f(u.x); a.y += b2f(u.y); a.z += b2f(u.z); a.w += b2f(u.w);
}

// accumulate 8 bf16 (one uint4) into two float4s
__device__ __forceinline__ void acc8(float4& lo, float4& hi, uint4 u) {
  lo.x += asF(u.x << 16); lo.y += asF(u.x & 0xffff0000u);
  lo.z += asF(u.y << 16); lo.w += asF(u.y & 0xffff0000u);
  hi.x += asF(u.z << 16); hi.y += asF(u.z & 0xffff0000u);
  hi.z += asF(u.w << 16); hi.w += asF(u.w & 0xffff0000u);
}

__device__ __forceinline__ float4 b2f4(ushort4 u) {
  return make_float4(b2f(u.x), b2f(u.y), b2f(u.z), b2f(u.w));
}

__device__ __forceinline__ float4 add4(float4 a, float4 b) {
  return make_float4(a.x + b.x, a.y + b.y, a.z + b.z, a.w + b.w);
}

// Build x0 [N,16] bf16: [node_h(9) | xg[batch](4) | 0,0,0]
__global__ void concat_kernel(const float* __restrict__ nh, const float* __restrict__ xg,
                              const int* __restrict__ batch, bf16* __restrict__ x0b) {
  int idx = blockIdx.x * blockDim.x + threadIdx.x;
  if (idx >= N_NODES * 16) return;
  int n = idx >> 4, j = idx & 15;
  float v;
  if (j < 9)       v = nh[n * 9 + j];
  else if (j < 13) v = xg[batch[n] * 4 + (j - 9)];
  else             v = 0.0f;
  x0b[idx] = __float2bfloat16(v);
}

// ---- CSR build via 2-level counting sort ----
__global__ __launch_bounds__(256) void bin_kernel(const int* __restrict__ src,
                                                  const int* __restrict__ dst,
                                                  int* __restrict__ gcnt,
                                                  int* __restrict__ binned) {
  __shared__ int hist[NB];
  __shared__ int base[NB];
  const int t = threadIdx.x;
  for (int i = t; i < NB; i += 256) hist[i] = 0;
  __syncthreads();
  const int e0 = blockIdx.x * EPB;
  int d[25];
#pragma unroll
  for (int k = 0; k < 25; ++k) {
    d[k] = dst[e0 + k * 256 + t];
    atomicAdd(&hist[d[k] >> 8], 1);
  }
  __syncthreads();
  for (int i = t; i < NB; i += 256) {
    base[i] = atomicAdd(&gcnt[i], hist[i]);
    hist[i] = 0;
  }
  __syncthreads();
#pragma unroll
  for (int k = 0; k < 25; ++k) {
    const int dd = d[k];
    const int b = dd >> 8;
    const int s = src[e0 + k * 256 + t];
    const int r = atomicAdd(&hist[b], 1);
    const int pos = base[b] + r;
    if (pos < BCAP) binned[b * BCAP + pos] = ((dd & 255) << 17) | s;
  }
}

__global__ __launch_bounds__(512) void bucketscan_kernel(const int* __restrict__ gcnt,
                                                         int* __restrict__ bbase,
                                                         int* __restrict__ rowptr) {
  __shared__ int sh[512];
  int t = threadIdx.x;
  int v = (t < NB) ? gcnt[t] : 0;
  sh[t] = v;
  __syncthreads();
  for (int off = 1; off < 512; off <<= 1) {
    int u = (t >= off) ? sh[t - off] : 0;
    __syncthreads();
    sh[t] += u;
    __syncthreads();
  }
  if (t < NB) bbase[t] = sh[t] - v;
  if (t == 0) rowptr[N_NODES] = N_EDGES;
}

__global__ __launch_bounds__(256) void sort_kernel(const int* __restrict__ gcnt,
                                                   const int* __restrict__ bbase,
                                                   const int* __restrict__ binned,
                                                   int* __restrict__ esorted,
                                                   int* __restrict__ rowptr,
                                                   float* __restrict__ inv) {
  __shared__ int cnt[256];
  __shared__ int cur[256];
  __shared__ int sh[256];
  const int b = blockIdx.x, t = threadIdx.x;
  const int count = min(gcnt[b], BCAP);
  const int ebase = bbase[b];
  const int* __restrict__ bin = binned + b * BCAP;
  cnt[t] = 0;
  __syncthreads();
  for (int i = t; i < count; i += 256) atomicAdd(&cnt[bin[i] >> 17], 1);
  __syncthreads();
  const int c = cnt[t];
  sh[t] = c;
  __syncthreads();
  for (int off = 1; off < 256; off <<= 1) {
    int u = (t >= off) ? sh[t - off] : 0;
    __syncthreads();
    sh[t] += u;
    __syncthreads();
  }
  const int p = sh[t] - c;
  cur[t] = p;
  const int node = b * 256 + t;
  if (node < N_NODES) {
    rowptr[node] = ebase + p;
    inv[node] = 1.0f / fmaxf((float)c, 1.0f);
  }
  __syncthreads();
  for (int i = t; i < count; i += 256) {
    const int v = bin[i];
    const int r = atomicAdd(&cur[v >> 17], 1);
    esorted[ebase + r] = v & 0x1FFFF;
  }
}

// ---- F=64 fused layer: 1024 threads = 16 waves, tile = 64 nodes ----
// Per node: 16 lanes = 2 edge-groups x 8 lanes; each lane loads uint4 (8 bf16)
// -> 8 rows in flight per wave load instr; group partials combine via shfl_xor(8).
// LDS: 32KB fp32 W + 32KB staging = 64KB -> 2 blocks/CU = 32 waves/CU (100% cap).
template <bool RELU, bool OUTF32>
__launch_bounds__(1024)
__global__ void sage64_kernel(const bf16* __restrict__ xb, const int* __restrict__ rowptr,
                              const int* __restrict__ esorted, const float* __restrict__ inv,
                              const float* __restrict__ Wl, const float* __restrict__ bl,
                              const float* __restrict__ Wr,
                              float* __restrict__ outf, bf16* __restrict__ outb) {
  constexpr int ST = 64;
  constexpr int NT = 64;
  __shared__ float Wlt[64 * 64];
  __shared__ float Wrt[64 * 64];
  __shared__ float asld[NT * ST];
  __shared__ float xsld[NT * ST];
  for (int i = threadIdx.x; i < 64 * 64; i += 1024) {
    int h = i & 63, f = i >> 6;  // consecutive lanes -> consecutive LDS words
    Wlt[f * 64 + h] = Wl[h * 64 + f];
    Wrt[f * 64 + h] = Wr[h * 64 + f];
  }
  __syncthreads();
  const int lane = threadIdx.x & 63;
  const int w = threadIdx.x >> 6;     // 0..15
  const int q = lane >> 4;            // node within wave (0..3)
  const int g = (lane >> 3) & 1;      // edge parity group
  const int c = lane & 7;             // 16B unit within 128B row
  const int slot = w * 4 + q;         // 0..63
  const float blv = bl[lane];
  const uint4* xb4 = (const uint4*)xb;  // 16B = 8 bf16
  const int ntiles = (N_NODES + NT - 1) / NT;  // 1563
  for (int tile = blockIdx.x; tile < ntiles; tile += gridDim.x) {
    const int n = tile * NT + slot;
    const bool valid = n < N_NODES;
    int e0 = 0, e1 = 0;
    float invn = 0.0f;
    uint4 uself = {0, 0, 0, 0};
    if (valid) {
      e0 = rowptr[n]; e1 = rowptr[n + 1]; invn = inv[n];
      if (g) uself = xb4[(size_t)n * 8 + c];  // self row via group 1 (parallel with agg)
    }
    float4 a0 = {0, 0, 0, 0}, a1 = a0, b0v = a0, b1v = a0;
    int e = e0 + g;
    for (; e + 6 < e1; e += 8) {  // this group handles e, e+2, e+4, e+6
      int s0 = esorted[e];
      int s1 = esorted[e + 2];
      int s2 = esorted[e + 4];
      int s3 = esorted[e + 6];
      uint4 u0 = xb4[(size_t)s0 * 8 + c];
      uint4 u1 = xb4[(size_t)s1 * 8 + c];
      uint4 u2 = xb4[(size_t)s2 * 8 + c];
      uint4 u3 = xb4[(size_t)s3 * 8 + c];
      acc8(a0, a1, u0); acc8(b0v, b1v, u1); acc8(a0, a1, u2); acc8(b0v, b1v, u3);
    }
    for (; e < e1; e += 2) {
      uint4 u = xb4[(size_t)esorted[e] * 8 + c];
      acc8(a0, a1, u);
    }
    a0 = add4(a0, b0v); a1 = add4(a1, b1v);
    // combine the two edge-groups (lane <-> lane^8)
    a0.x += __shfl_xor(a0.x, 8); a0.y += __shfl_xor(a0.y, 8);
    a0.z += __shfl_xor(a0.z, 8); a0.w += __shfl_xor(a0.w, 8);
    a1.x += __shfl_xor(a1.x, 8); a1.y += __shfl_xor(a1.y, 8);
    a1.z += __shfl_xor(a1.z, 8); a1.w += __shfl_xor(a1.w, 8);
    if (g == 0) {  // group 0 writes agg
      a0.x *= invn; a0.y *= invn; a0.z *= invn; a0.w *= invn;
      a1.x *= invn; a1.y *= invn; a1.z *= invn; a1.w *= invn;
      *(float4*)&asld[slot * ST + 8 * c]     = a0;
      *(float4*)&asld[slot * ST + 8 * c + 4] = a1;
    } else {       // group 1 unpacks + writes self row
      float4 x0v, x1v;
      x0v.x = asF(uself.x << 16); x0v.y = asF(uself.x & 0xffff0000u);
      x0v.z = asF(uself.y << 16); x0v.w = asF(uself.y & 0xffff0000u);
      x1v.x = asF(uself.z << 16); x1v.y = asF(uself.z & 0xffff0000u);
      x1v.z = asF(uself.w << 16); x1v.w = asF(uself.w & 0xffff0000u);
      *(float4*)&xsld[slot * ST + 8 * c]     = x0v;
      *(float4*)&xsld[slot * ST + 8 * c + 4] = x1v;
    }
    // wave-local LDS produce->consume (wave w only touches slots w*4..w*4+3)
    __builtin_amdgcn_wave_barrier();
    const float* ar0 = &asld[(w * 4 + 0) * ST];
    const float* ar1 = &asld[(w * 4 + 1) * ST];
    const float* ar2 = &asld[(w * 4 + 2) * ST];
    const float* ar3 = &asld[(w * 4 + 3) * ST];
    const float* xr0 = &xsld[(w * 4 + 0) * ST];
    const float* xr1 = &xsld[(w * 4 + 1) * ST];
    const float* xr2 = &xsld[(w * 4 + 2) * ST];
    const float* xr3 = &xsld[(w * 4 + 3) * ST];
    float o0 = blv, o1 = blv, o2 = blv, o3 = blv;
#pragma unroll
    for (int f = 0; f < 64; ++f) {
      float wl = Wlt[f * 64 + lane];
      float wr = Wrt[f * 64 + lane];
      o0 = fmaf(ar0[f], wl, fmaf(xr0[f], wr, o0));
      o1 = fmaf(ar1[f], wl, fmaf(xr1[f], wr, o1));
      o2 = fmaf(ar2[f], wl, fmaf(xr2[f], wr, o2));
      o3 = fmaf(ar3[f], wl, fmaf(xr3[f], wr, o3));
    }
    if (RELU) {
      o0 = fmaxf(o0, 0.0f); o1 = fmaxf(o1, 0.0f);
      o2 = fmaxf(o2, 0.0f); o3 = fmaxf(o3, 0.0f);
    }
    const int nbase = tile * NT + w * 4;
    if (nbase < N_NODES) {  // validity boundary (32) is a multiple of 4
      const size_t nb = (size_t)nbase * 64;
      if (OUTF32) {
        outf[nb + lane]       = o0;
        outf[nb + 64 + lane]  = o1;
        outf[nb + 128 + lane] = o2;
        outf[nb + 192 + lane] = o3;
      } else {
        outb[nb + lane]       = __float2bfloat16(o0);
        outb[nb + 64 + lane]  = __float2bfloat16(o1);
        outb[nb + 128 + lane] = __float2bfloat16(o2);
        outb[nb + 192 + lane] = __float2bfloat16(o3);
      }
    }
    __builtin_amdgcn_wave_barrier();
  }
}

// ---- F=16 fused layer 0 (512 threads, tile=32, 8B gathers) ----
__launch_bounds__(512)
__global__ void sage16_kernel(const bf16* __restrict__ xb, const int* __restrict__ rowptr,
                              const int* __restrict__ esorted, const float* __restrict__ inv,
                              const float* __restrict__ Wl, const float* __restrict__ bl,
                              const float* __restrict__ Wr, int Fw, bf16* __restrict__ outb) {
  constexpr int F = 16, ST = 20, NT = 32;
  __shared__ float Wlt[F * 64];
  __shared__ float Wrt[F * 64];
  __shared__ float asld[NT * ST];
  __shared__ float xsld[NT * ST];
  for (int i = threadIdx.x; i < 64 * F; i += 512) {
    int h = i & 63, f = i >> 6;
    Wlt[f * 64 + h] = (f < Fw) ? Wl[h * Fw + f] : 0.0f;
    Wrt[f * 64 + h] = (f < Fw) ? Wr[h * Fw + f] : 0.0f;
  }
  __syncthreads();
  const int lane = threadIdx.x & 63;
  const int w = threadIdx.x >> 6;
  const int q = lane >> 4;
  const int c = lane & 15;
  const int slot = w * 4 + q;
  const float blv = bl[lane];
  const ushort4* xbu = (const ushort4*)xb;
  const int ntiles = N_NODES / NT;  // 3125
  for (int tile = blockIdx.x; tile < ntiles; tile += gridDim.x) {
    const int n = tile * NT + slot;
    const int e0 = rowptr[n], e1 = rowptr[n + 1];
    const float invn = inv[n];
    const int eg = c >> 2, cc = c & 3;
    float4 a0 = {0, 0, 0, 0}, a1 = a0;
    int e = e0 + eg;
    for (; e + 4 < e1; e += 8) {
      int sa = esorted[e], sb = esorted[e + 4];
      ushort4 ua = xbu[(size_t)sa * 4 + cc];
      ushort4 ub = xbu[(size_t)sb * 4 + cc];
      accb(a0, ua); accb(a1, ub);
    }
    if (e < e1) accb(a0, xbu[(size_t)esorted[e] * 4 + cc]);
    a0 = add4(a0, a1);
    a0.x += __shfl_xor(a0.x, 4); a0.y += __shfl_xor(a0.y, 4);
    a0.z += __shfl_xor(a0.z, 4); a0.w += __shfl_xor(a0.w, 4);
    a0.x += __shfl_xor(a0.x, 8); a0.y += __shfl_xor(a0.y, 8);
    a0.z += __shfl_xor(a0.z, 8); a0.w += __shfl_xor(a0.w, 8);
    if (eg == 0) {
      float4 xv = b2f4(xbu[(size_t)n * 4 + cc]);
      a0.x *= invn; a0.y *= invn; a0.z *= invn; a0.w *= invn;
      *(float4*)&asld[slot * ST + 4 * cc] = a0;
      *(float4*)&xsld[slot * ST + 4 * cc] = xv;
    }
    __builtin_amdgcn_wave_barrier();
    const float* ar0 = &asld[(w * 4 + 0) * ST];
    const float* ar1 = &asld[(w * 4 + 1) * ST];
    const float* ar2 = &asld[(w * 4 + 2) * ST];
    const float* ar3 = &asld[(w * 4 + 3) * ST];
    const float* xr0 = &xsld[(w * 4 + 0) * ST];
    const float* xr1 = &xsld[(w * 4 + 1) * ST];
    const float* xr2 = &xsld[(w * 4 + 2) * ST];
    const float* xr3 = &xsld[(w * 4 + 3) * ST];
    float o0 = blv, o1 = blv, o2 = blv, o3 = blv;
#pragma unroll
    for (int f = 0; f < F; ++f) {
      float wl = Wlt[f * 64 + lane];
      float wr = Wrt[f * 64 + lane];
      o0 = fmaf(ar0[f], wl, fmaf(xr0[f], wr, o0));
      o1 = fmaf(ar1[f], wl, fmaf(xr1[f], wr, o1));
      o2 = fmaf(ar2[f], wl, fmaf(xr2[f], wr, o2));
      o3 = fmaf(ar3[f], wl, fmaf(xr3[f], wr, o3));
    }
    o0 = fmaxf(o0, 0.0f); o1 = fmaxf(o1, 0.0f);
    o2 = fmaxf(o2, 0.0f); o3 = fmaxf(o3, 0.0f);
    const size_t nb = (size_t)(tile * NT + w * 4) * 64;
    outb[nb + lane]       = __float2bfloat16(o0);
    outb[nb + 64 + lane]  = __float2bfloat16(o1);
    outb[nb + 128 + lane] = __float2bfloat16(o2);
    outb[nb + 192 + lane] = __float2bfloat16(o3);
    __builtin_amdgcn_wave_barrier();
  }
}

// scatter-mean pooling: batch_idx sorted -> run-detection
__global__ void pool_kernel(const float* __restrict__ x, const int* __restrict__ batch,
                            float* __restrict__ pooled, float* __restrict__ cnt) {
  int wave = (blockIdx.x * blockDim.x + threadIdx.x) >> 6;
  int lane = threadIdx.x & 63;
  int n0 = wave * 64;
  if (n0 >= N_NODES) return;
  int nend = n0 + 64 < N_NODES ? n0 + 64 : N_NODES;
  int cur = -1;
  float acc = 0.0f, run = 0.0f;
  for (int n = n0; n < nend; ++n) {
    int b = batch[n];
    float v = x[(size_t)n * 64 + lane];
    if (b != cur) {
      if (cur >= 0) {
        atomAddF(&pooled[cur * 64 + lane], acc);
        if (lane == 0) atomAddF(&cnt[cur], run);
      }
      cur = b; acc = v; run = 1.0f;
    } else {
      acc += v; run += 1.0f;
    }
  }
  if (cur >= 0) {
    atomAddF(&pooled[cur * 64 + lane], acc);
    if (lane == 0) atomAddF(&cnt[cur], run);
  }
}

// per-graph MLP 64->64->64->64->1
__global__ void mlp_kernel(const float* __restrict__ pooled, const float* __restrict__ cnt,
                           const float* __restrict__ W0, const float* __restrict__ b0,
                           const float* __restrict__ W1, const float* __restrict__ b1,
                           const float* __restrict__ W2, const float* __restrict__ b2,
                           const float* __restrict__ W3, const float* __restrict__ b3,
                           float* __restrict__ out) {
  int g = blockIdx.x, t = threadIdx.x;
  __shared__ float buf[2][64];
  float ic = 1.0f / fmaxf(cnt[g], 1.0f);
  buf[0][t] = pooled[g * 64 + t] * ic;
  __syncthreads();
  const float* Ws[3] = {W0, W1, W2};
  const float* Bs[3] = {b0, b1, b2};
  int cur = 0;
  for (int L = 0; L < 3; ++L) {
    const float* W = Ws[L];
    float acc = Bs[L][t];
#pragma unroll
    for (int f = 0; f < 64; ++f) acc = fmaf(W[t * 64 + f], buf[cur][f], acc);
    buf[cur ^ 1][t] = fmaxf(acc, 0.0f);
    __syncthreads();
    cur ^= 1;
  }
  float v = W3[t] * buf[cur][t];
  for (int off = 32; off; off >>= 1) v += __shfl_down(v, off);
  if (t == 0) out[g] = v + b3[0];
}

extern "C" void kernel_launch(void* const* d_in, const int* in_sizes, int n_in,
                              void* d_out, int out_size, void* d_ws, size_t ws_size,
                              hipStream_t stream) {
  const float* nh    = (const float*)d_in[0];
  const float* xg    = (const float*)d_in[1];
  const int*   ei    = (const int*)d_in[2];
  const int*   batch = (const int*)d_in[3];
  const float* s0Wl  = (const float*)d_in[4];
  const float* s0bl  = (const float*)d_in[5];
  const float* s0Wr  = (const float*)d_in[6];
  const float* s1Wl  = (const float*)d_in[7];
  const float* s1bl  = (const float*)d_in[8];
  const float* s1Wr  = (const float*)d_in[9];
  const float* s2Wl  = (const float*)d_in[10];
  const float* s2bl  = (const float*)d_in[11];
  const float* s2Wr  = (const float*)d_in[12];
  const float* mW0   = (const float*)d_in[13];
  const float* mb0   = (const float*)d_in[14];
  const float* mW1   = (const float*)d_in[15];
  const float* mb1   = (const float*)d_in[16];
  const float* mW2   = (const float*)d_in[17];
  const float* mb2   = (const float*)d_in[18];
  const float* mW3   = (const float*)d_in[19];
  const float* mb3   = (const float*)d_in[20];

  const int* src = ei;
  const int* dst = ei + N_EDGES;

  // ws layout (float units; every region start is 16B-aligned)
  float* B0f    = (float*)d_ws;                       // N*64 f32 (final layer out)
  bf16*  x0b    = (bf16*)(B0f + (size_t)N_NODES * 64);          // N*16 bf16
  bf16*  B0b    = (bf16*)((float*)x0b + (size_t)N_NODES * 8);   // N*64 bf16
  bf16*  B1b    = (bf16*)((float*)B0b + (size_t)N_NODES * 32);  // N*64 bf16
  float* inv    = (float*)B1b + (size_t)N_NODES * 32; // N
  float* pooled = inv + N_NODES;                      // 250*64
  float* cnt    = pooled + (size_t)N_GRAPHS * 64;     // 250 (pad 256)
  int*   rowptr  = (int*)(cnt + 256);                 // N+1 (pad 100004)
  int*   esorted = rowptr + 100004;                   // E
  int*   gcnt    = esorted + N_EDGES;                 // NB (pad 400)
  int*   bbase   = gcnt + 400;                        // NB (pad 400)
  int*   binned  = (int*)B1b;                         // NB*BCAP ints (9.6MB <= B1b's 12.8MB;
                                                      // consumed by sort before L1 writes B1b)

  hipMemsetAsync(gcnt, 0, NB * sizeof(int), stream);
  hipMemsetAsync(pooled, 0, (N_GRAPHS * 64 + N_GRAPHS) * sizeof(float), stream);

  // CSR build: 2-level counting sort
  bin_kernel<<<BIN_BLOCKS, 256, 0, stream>>>(src, dst, gcnt, binned);
  bucketscan_kernel<<<1, 512, 0, stream>>>(gcnt, bbase, rowptr);
  sort_kernel<<<NB, 256, 0, stream>>>(gcnt, bbase, binned, esorted, rowptr, inv);

  // x0 bf16
  concat_kernel<<<(N_NODES * 16 + 255) / 256, 256, 0, stream>>>(nh, xg, batch, x0b);

  // fused layers: x0b -> B0b -> B1b -> B0f
  sage16_kernel<<<1024, 512, 0, stream>>>(x0b, rowptr, esorted, inv,
                                          s0Wl, s0bl, s0Wr, 13, B0b);
  sage64_kernel<true, false><<<512, 1024, 0, stream>>>(B0b, rowptr, esorted, inv,
                                                       s1Wl, s1bl, s1Wr, nullptr, B1b);
  sage64_kernel<false, true><<<512, 1024, 0, stream>>>(B1b, rowptr, esorted, inv,
                                                       s2Wl, s2bl, s2Wr, B0f, nullptr);

  // pooling + MLP
  pool_kernel<<<((N_NODES + 63) / 64 * 64 + 255) / 256, 256, 0, stream>>>(B0f, batch, pooled, cnt);
  mlp_kernel<<<N_GRAPHS, 64, 0, stream>>>(pooled, cnt, mW0, mb0, mW1, mb1, mW2, mb2, mW3, mb3,
                                          (float*)d_out);
}

// Round 14
// 361.345 us; speedup vs baseline: 1.7241x; 1.0202x over previous
//
#include <hip/hip_runtime.h>
#include <hip/hip_bf16.h>

#define N_NODES 100000
#define N_EDGES 1600000
#define N_GRAPHS 250
#define NB 391          // buckets of 256 nodes: bucket = dst >> 8
#define BCAP 6144       // bucket capacity (mean 4092, sigma ~64)
#define BIN_BLOCKS 250
#define EPB 6400        // edges per bin block (25 per thread)

typedef __hip_bfloat16 bf16;

__device__ __forceinline__ void atomAddF(float* p, float v) {
  unsafeAtomicAdd(p, v);
}

__device__ __forceinline__ float b2f(unsigned short u) {
  union { unsigned int i; float f; } v; v.i = ((unsigned)u) << 16; return v.f;
}

__device__ __forceinline__ float asF(unsigned int i) {
  union { unsigned int i; float f; } v; v.i = i; return v.f;
}

__device__ __forceinline__ void accb(float4& a, ushort4 u) {
  a.x += b2f(u.x); a.y += b2f(u.y); a.z += b2f(u.z); a.w += b2f(u.w);
}

// accumulate 8 bf16 (one uint4) into two float4s
__device__ __forceinline__ void acc8(float4& lo, float4& hi, uint4 u) {
  lo.x += asF(u.x << 16); lo.y += asF(u.x & 0xffff0000u);
  lo.z += asF(u.y << 16); lo.w += asF(u.y & 0xffff0000u);
  hi.x += asF(u.z << 16); hi.y += asF(u.z & 0xffff0000u);
  hi.z += asF(u.w << 16); hi.w += asF(u.w & 0xffff0000u);
}

__device__ __forceinline__ float4 b2f4(ushort4 u) {
  return make_float4(b2f(u.x), b2f(u.y), b2f(u.z), b2f(u.w));
}

__device__ __forceinline__ float4 add4(float4 a, float4 b) {
  return make_float4(a.x + b.x, a.y + b.y, a.z + b.z, a.w + b.w);
}

// Build x0 [N,16] bf16: [node_h(9) | xg[batch](4) | 0,0,0]
__global__ void concat_kernel(const float* __restrict__ nh, const float* __restrict__ xg,
                              const int* __restrict__ batch, bf16* __restrict__ x0b) {
  int idx = blockIdx.x * blockDim.x + threadIdx.x;
  if (idx >= N_NODES * 16) return;
  int n = idx >> 4, j = idx & 15;
  float v;
  if (j < 9)       v = nh[n * 9 + j];
  else if (j < 13) v = xg[batch[n] * 4 + (j - 9)];
  else             v = 0.0f;
  x0b[idx] = __float2bfloat16(v);
}

// ---- CSR build via 2-level counting sort ----
__global__ __launch_bounds__(256) void bin_kernel(const int* __restrict__ src,
                                                  const int* __restrict__ dst,
                                                  int* __restrict__ gcnt,
                                                  int* __restrict__ binned) {
  __shared__ int hist[NB];
  __shared__ int base[NB];
  const int t = threadIdx.x;
  for (int i = t; i < NB; i += 256) hist[i] = 0;
  __syncthreads();
  const int e0 = blockIdx.x * EPB;
  int d[25];
#pragma unroll
  for (int k = 0; k < 25; ++k) {
    d[k] = dst[e0 + k * 256 + t];
    atomicAdd(&hist[d[k] >> 8], 1);
  }
  __syncthreads();
  for (int i = t; i < NB; i += 256) {
    base[i] = atomicAdd(&gcnt[i], hist[i]);
    hist[i] = 0;
  }
  __syncthreads();
#pragma unroll
  for (int k = 0; k < 25; ++k) {
    const int dd = d[k];
    const int b = dd >> 8;
    const int s = src[e0 + k * 256 + t];
    const int r = atomicAdd(&hist[b], 1);
    const int pos = base[b] + r;
    if (pos < BCAP) binned[b * BCAP + pos] = ((dd & 255) << 17) | s;
  }
}

__global__ __launch_bounds__(512) void bucketscan_kernel(const int* __restrict__ gcnt,
                                                         int* __restrict__ bbase,
                                                         int* __restrict__ rowptr) {
  __shared__ int sh[512];
  int t = threadIdx.x;
  int v = (t < NB) ? gcnt[t] : 0;
  sh[t] = v;
  __syncthreads();
  for (int off = 1; off < 512; off <<= 1) {
    int u = (t >= off) ? sh[t - off] : 0;
    __syncthreads();
    sh[t] += u;
    __syncthreads();
  }
  if (t < NB) bbase[t] = sh[t] - v;
  if (t == 0) rowptr[N_NODES] = N_EDGES;
}

__global__ __launch_bounds__(256) void sort_kernel(const int* __restrict__ gcnt,
                                                   const int* __restrict__ bbase,
                                                   const int* __restrict__ binned,
                                                   int* __restrict__ esorted,
                                                   int* __restrict__ rowptr,
                                                   float* __restrict__ inv) {
  __shared__ int cnt[256];
  __shared__ int cur[256];
  __shared__ int sh[256];
  const int b = blockIdx.x, t = threadIdx.x;
  const int count = min(gcnt[b], BCAP);
  const int ebase = bbase[b];
  const int* __restrict__ bin = binned + b * BCAP;
  cnt[t] = 0;
  __syncthreads();
  for (int i = t; i < count; i += 256) atomicAdd(&cnt[bin[i] >> 17], 1);
  __syncthreads();
  const int c = cnt[t];
  sh[t] = c;
  __syncthreads();
  for (int off = 1; off < 256; off <<= 1) {
    int u = (t >= off) ? sh[t - off] : 0;
    __syncthreads();
    sh[t] += u;
    __syncthreads();
  }
  const int p = sh[t] - c;
  cur[t] = p;
  const int node = b * 256 + t;
  if (node < N_NODES) {
    rowptr[node] = ebase + p;
    inv[node] = 1.0f / fmaxf((float)c, 1.0f);
  }
  __syncthreads();
  for (int i = t; i < count; i += 256) {
    const int v = bin[i];
    const int r = atomicAdd(&cur[v >> 17], 1);
    esorted[ebase + r] = v & 0x1FFFF;
  }
}

// ---- F=64 fused layer: 1024 threads = 16 waves, tile = 64 nodes ----
// Per node: 16 lanes = 2 edge-groups x 8 lanes; contiguous half-range per group
// (sequential esorted addresses); each lane loads uint4 (8 bf16).
// W stored interleaved float2 {wl,wr} -> one ds_read_b64 per f in the transform.
template <bool RELU, bool OUTF32>
__launch_bounds__(1024)
__global__ void sage64_kernel(const bf16* __restrict__ xb, const int* __restrict__ rowptr,
                              const int* __restrict__ esorted, const float* __restrict__ inv,
                              const float* __restrict__ Wl, const float* __restrict__ bl,
                              const float* __restrict__ Wr,
                              float* __restrict__ outf, bf16* __restrict__ outb) {
  constexpr int ST = 64;
  constexpr int NT = 64;
  __shared__ float2 WB[64 * 64];   // 32KB: {wl, wr} per (f, h)
  __shared__ float asld[NT * ST];  // 16KB
  __shared__ float xsld[NT * ST];  // 16KB
  for (int i = threadIdx.x; i < 64 * 64; i += 1024) {
    int h = i & 63, f = i >> 6;  // consecutive lanes -> consecutive float2 (2-way = free)
    WB[f * 64 + h] = make_float2(Wl[h * 64 + f], Wr[h * 64 + f]);
  }
  __syncthreads();
  const int lane = threadIdx.x & 63;
  const int w = threadIdx.x >> 6;     // 0..15
  const int q = lane >> 4;            // node within wave (0..3)
  const int g = (lane >> 3) & 1;      // edge half-group
  const int c = lane & 7;             // 16B unit within 128B row
  const int slot = w * 4 + q;         // 0..63
  const float blv = bl[lane];
  const uint4* xb4 = (const uint4*)xb;  // 16B = 8 bf16
  const int ntiles = (N_NODES + NT - 1) / NT;  // 1563
  for (int tile = blockIdx.x; tile < ntiles; tile += gridDim.x) {
    const int n = tile * NT + slot;
    const bool valid = n < N_NODES;
    int e0 = 0, deg = 0;
    float invn = 0.0f;
    uint4 uself = {0, 0, 0, 0};
    if (valid) {
      e0 = rowptr[n]; deg = rowptr[n + 1] - e0; invn = inv[n];
      if (g) uself = xb4[(size_t)n * 8 + c];  // self row via group 1
    }
    // contiguous halves: group0 [e0, mid), group1 [mid, e0+deg)
    const int mid = e0 + ((deg + 1) >> 1);
    int lo = g ? mid : e0;
    const int hi = g ? (e0 + deg) : mid;
    float4 a0 = {0, 0, 0, 0}, a1 = a0, b0v = a0, b1v = a0;
    for (; lo + 4 <= hi; lo += 4) {
      int s0 = esorted[lo];
      int s1 = esorted[lo + 1];
      int s2 = esorted[lo + 2];
      int s3 = esorted[lo + 3];
      uint4 u0 = xb4[(size_t)s0 * 8 + c];
      uint4 u1 = xb4[(size_t)s1 * 8 + c];
      uint4 u2 = xb4[(size_t)s2 * 8 + c];
      uint4 u3 = xb4[(size_t)s3 * 8 + c];
      acc8(a0, a1, u0); acc8(b0v, b1v, u1); acc8(a0, a1, u2); acc8(b0v, b1v, u3);
    }
    for (; lo < hi; ++lo) {
      uint4 u = xb4[(size_t)esorted[lo] * 8 + c];
      acc8(a0, a1, u);
    }
    a0 = add4(a0, b0v); a1 = add4(a1, b1v);
    // combine the two edge-groups (lane <-> lane^8)
    a0.x += __shfl_xor(a0.x, 8); a0.y += __shfl_xor(a0.y, 8);
    a0.z += __shfl_xor(a0.z, 8); a0.w += __shfl_xor(a0.w, 8);
    a1.x += __shfl_xor(a1.x, 8); a1.y += __shfl_xor(a1.y, 8);
    a1.z += __shfl_xor(a1.z, 8); a1.w += __shfl_xor(a1.w, 8);
    if (g == 0) {  // group 0 writes agg
      a0.x *= invn; a0.y *= invn; a0.z *= invn; a0.w *= invn;
      a1.x *= invn; a1.y *= invn; a1.z *= invn; a1.w *= invn;
      *(float4*)&asld[slot * ST + 8 * c]     = a0;
      *(float4*)&asld[slot * ST + 8 * c + 4] = a1;
    } else {       // group 1 unpacks + writes self row
      float4 x0v, x1v;
      x0v.x = asF(uself.x << 16); x0v.y = asF(uself.x & 0xffff0000u);
      x0v.z = asF(uself.y << 16); x0v.w = asF(uself.y & 0xffff0000u);
      x1v.x = asF(uself.z << 16); x1v.y = asF(uself.z & 0xffff0000u);
      x1v.z = asF(uself.w << 16); x1v.w = asF(uself.w & 0xffff0000u);
      *(float4*)&xsld[slot * ST + 8 * c]     = x0v;
      *(float4*)&xsld[slot * ST + 8 * c + 4] = x1v;
    }
    // wave-local LDS produce->consume (wave w only touches slots w*4..w*4+3)
    __builtin_amdgcn_wave_barrier();
    const float* ar0 = &asld[(w * 4 + 0) * ST];
    const float* ar1 = &asld[(w * 4 + 1) * ST];
    const float* ar2 = &asld[(w * 4 + 2) * ST];
    const float* ar3 = &asld[(w * 4 + 3) * ST];
    const float* xr0 = &xsld[(w * 4 + 0) * ST];
    const float* xr1 = &xsld[(w * 4 + 1) * ST];
    const float* xr2 = &xsld[(w * 4 + 2) * ST];
    const float* xr3 = &xsld[(w * 4 + 3) * ST];
    float o0 = blv, o1 = blv, o2 = blv, o3 = blv;
#pragma unroll
    for (int f = 0; f < 64; ++f) {
      const float2 wv = WB[f * 64 + lane];  // single b64 read: {wl, wr}
      o0 = fmaf(ar0[f], wv.x, fmaf(xr0[f], wv.y, o0));
      o1 = fmaf(ar1[f], wv.x, fmaf(xr1[f], wv.y, o1));
      o2 = fmaf(ar2[f], wv.x, fmaf(xr2[f], wv.y, o2));
      o3 = fmaf(ar3[f], wv.x, fmaf(xr3[f], wv.y, o3));
    }
    if (RELU) {
      o0 = fmaxf(o0, 0.0f); o1 = fmaxf(o1, 0.0f);
      o2 = fmaxf(o2, 0.0f); o3 = fmaxf(o3, 0.0f);
    }
    const int nbase = tile * NT + w * 4;
    if (nbase < N_NODES) {  // validity boundary (32) is a multiple of 4
      const size_t nb = (size_t)nbase * 64;
      if (OUTF32) {
        outf[nb + lane]       = o0;
        outf[nb + 64 + lane]  = o1;
        outf[nb + 128 + lane] = o2;
        outf[nb + 192 + lane] = o3;
      } else {
        outb[nb + lane]       = __float2bfloat16(o0);
        outb[nb + 64 + lane]  = __float2bfloat16(o1);
        outb[nb + 128 + lane] = __float2bfloat16(o2);
        outb[nb + 192 + lane] = __float2bfloat16(o3);
      }
    }
    __builtin_amdgcn_wave_barrier();
  }
}

// ---- F=16 fused layer 0 (512 threads, tile=32, contiguous quarter-ranges) ----
__launch_bounds__(512)
__global__ void sage16_kernel(const bf16* __restrict__ xb, const int* __restrict__ rowptr,
                              const int* __restrict__ esorted, const float* __restrict__ inv,
                              const float* __restrict__ Wl, const float* __restrict__ bl,
                              const float* __restrict__ Wr, int Fw, bf16* __restrict__ outb) {
  constexpr int F = 16, ST = 20, NT = 32;
  __shared__ float2 WB[F * 64];   // 8KB {wl, wr}
  __shared__ float asld[NT * ST];
  __shared__ float xsld[NT * ST];
  for (int i = threadIdx.x; i < 64 * F; i += 512) {
    int h = i & 63, f = i >> 6;
    WB[f * 64 + h] = make_float2((f < Fw) ? Wl[h * Fw + f] : 0.0f,
                                 (f < Fw) ? Wr[h * Fw + f] : 0.0f);
  }
  __syncthreads();
  const int lane = threadIdx.x & 63;
  const int w = threadIdx.x >> 6;
  const int q = lane >> 4;
  const int c = lane & 15;
  const int slot = w * 4 + q;
  const float blv = bl[lane];
  const ushort4* xbu = (const ushort4*)xb;
  const int ntiles = N_NODES / NT;  // 3125
  for (int tile = blockIdx.x; tile < ntiles; tile += gridDim.x) {
    const int n = tile * NT + slot;
    const int e0 = rowptr[n], e1 = rowptr[n + 1];
    const int deg = e1 - e0;
    const float invn = inv[n];
    const int eg = c >> 2, cc = c & 3;
    // contiguous quarter-ranges per edge-group
    int lo = e0 + ((deg * eg) >> 2);
    const int hi = e0 + ((deg * (eg + 1)) >> 2);
    float4 a0 = {0, 0, 0, 0}, a1 = a0;
    for (; lo + 2 <= hi; lo += 2) {
      int sa = esorted[lo], sb = esorted[lo + 1];
      ushort4 ua = xbu[(size_t)sa * 4 + cc];
      ushort4 ub = xbu[(size_t)sb * 4 + cc];
      accb(a0, ua); accb(a1, ub);
    }
    if (lo < hi) accb(a0, xbu[(size_t)esorted[lo] * 4 + cc]);
    a0 = add4(a0, a1);
    a0.x += __shfl_xor(a0.x, 4); a0.y += __shfl_xor(a0.y, 4);
    a0.z += __shfl_xor(a0.z, 4); a0.w += __shfl_xor(a0.w, 4);
    a0.x += __shfl_xor(a0.x, 8); a0.y += __shfl_xor(a0.y, 8);
    a0.z += __shfl_xor(a0.z, 8); a0.w += __shfl_xor(a0.w, 8);
    if (eg == 0) {
      float4 xv = b2f4(xbu[(size_t)n * 4 + cc]);
      a0.x *= invn; a0.y *= invn; a0.z *= invn; a0.w *= invn;
      *(float4*)&asld[slot * ST + 4 * cc] = a0;
      *(float4*)&xsld[slot * ST + 4 * cc] = xv;
    }
    __builtin_amdgcn_wave_barrier();
    const float* ar0 = &asld[(w * 4 + 0) * ST];
    const float* ar1 = &asld[(w * 4 + 1) * ST];
    const float* ar2 = &asld[(w * 4 + 2) * ST];
    const float* ar3 = &asld[(w * 4 + 3) * ST];
    const float* xr0 = &xsld[(w * 4 + 0) * ST];
    const float* xr1 = &xsld[(w * 4 + 1) * ST];
    const float* xr2 = &xsld[(w * 4 + 2) * ST];
    const float* xr3 = &xsld[(w * 4 + 3) * ST];
    float o0 = blv, o1 = blv, o2 = blv, o3 = blv;
#pragma unroll
    for (int f = 0; f < F; ++f) {
      const float2 wv = WB[f * 64 + lane];
      o0 = fmaf(ar0[f], wv.x, fmaf(xr0[f], wv.y, o0));
      o1 = fmaf(ar1[f], wv.x, fmaf(xr1[f], wv.y, o1));
      o2 = fmaf(ar2[f], wv.x, fmaf(xr2[f], wv.y, o2));
      o3 = fmaf(ar3[f], wv.x, fmaf(xr3[f], wv.y, o3));
    }
    o0 = fmaxf(o0, 0.0f); o1 = fmaxf(o1, 0.0f);
    o2 = fmaxf(o2, 0.0f); o3 = fmaxf(o3, 0.0f);
    const size_t nb = (size_t)(tile * NT + w * 4) * 64;
    outb[nb + lane]       = __float2bfloat16(o0);
    outb[nb + 64 + lane]  = __float2bfloat16(o1);
    outb[nb + 128 + lane] = __float2bfloat16(o2);
    outb[nb + 192 + lane] = __float2bfloat16(o3);
    __builtin_amdgcn_wave_barrier();
  }
}

// scatter-mean pooling: batch_idx sorted -> run-detection
__global__ void pool_kernel(const float* __restrict__ x, const int* __restrict__ batch,
                            float* __restrict__ pooled, float* __restrict__ cnt) {
  int wave = (blockIdx.x * blockDim.x + threadIdx.x) >> 6;
  int lane = threadIdx.x & 63;
  int n0 = wave * 64;
  if (n0 >= N_NODES) return;
  int nend = n0 + 64 < N_NODES ? n0 + 64 : N_NODES;
  int cur = -1;
  float acc = 0.0f, run = 0.0f;
  for (int n = n0; n < nend; ++n) {
    int b = batch[n];
    float v = x[(size_t)n * 64 + lane];
    if (b != cur) {
      if (cur >= 0) {
        atomAddF(&pooled[cur * 64 + lane], acc);
        if (lane == 0) atomAddF(&cnt[cur], run);
      }
      cur = b; acc = v; run = 1.0f;
    } else {
      acc += v; run += 1.0f;
    }
  }
  if (cur >= 0) {
    atomAddF(&pooled[cur * 64 + lane], acc);
    if (lane == 0) atomAddF(&cnt[cur], run);
  }
}

// per-graph MLP 64->64->64->64->1
__global__ void mlp_kernel(const float* __restrict__ pooled, const float* __restrict__ cnt,
                           const float* __restrict__ W0, const float* __restrict__ b0,
                           const float* __restrict__ W1, const float* __restrict__ b1,
                           const float* __restrict__ W2, const float* __restrict__ b2,
                           const float* __restrict__ W3, const float* __restrict__ b3,
                           float* __restrict__ out) {
  int g = blockIdx.x, t = threadIdx.x;
  __shared__ float buf[2][64];
  float ic = 1.0f / fmaxf(cnt[g], 1.0f);
  buf[0][t] = pooled[g * 64 + t] * ic;
  __syncthreads();
  const float* Ws[3] = {W0, W1, W2};
  const float* Bs[3] = {b0, b1, b2};
  int cur = 0;
  for (int L = 0; L < 3; ++L) {
    const float* W = Ws[L];
    float acc = Bs[L][t];
#pragma unroll
    for (int f = 0; f < 64; ++f) acc = fmaf(W[t * 64 + f], buf[cur][f], acc);
    buf[cur ^ 1][t] = fmaxf(acc, 0.0f);
    __syncthreads();
    cur ^= 1;
  }
  float v = W3[t] * buf[cur][t];
  for (int off = 32; off; off >>= 1) v += __shfl_down(v, off);
  if (t == 0) out[g] = v + b3[0];
}

extern "C" void kernel_launch(void* const* d_in, const int* in_sizes, int n_in,
                              void* d_out, int out_size, void* d_ws, size_t ws_size,
                              hipStream_t stream) {
  const float* nh    = (const float*)d_in[0];
  const float* xg    = (const float*)d_in[1];
  const int*   ei    = (const int*)d_in[2];
  const int*   batch = (const int*)d_in[3];
  const float* s0Wl  = (const float*)d_in[4];
  const float* s0bl  = (const float*)d_in[5];
  const float* s0Wr  = (const float*)d_in[6];
  const float* s1Wl  = (const float*)d_in[7];
  const float* s1bl  = (const float*)d_in[8];
  const float* s1Wr  = (const float*)d_in[9];
  const float* s2Wl  = (const float*)d_in[10];
  const float* s2bl  = (const float*)d_in[11];
  const float* s2Wr  = (const float*)d_in[12];
  const float* mW0   = (const float*)d_in[13];
  const float* mb0   = (const float*)d_in[14];
  const float* mW1   = (const float*)d_in[15];
  const float* mb1   = (const float*)d_in[16];
  const float* mW2   = (const float*)d_in[17];
  const float* mb2   = (const float*)d_in[18];
  const float* mW3   = (const float*)d_in[19];
  const float* mb3   = (const float*)d_in[20];

  const int* src = ei;
  const int* dst = ei + N_EDGES;

  // ws layout (float units; every region start is 16B-aligned)
  float* B0f    = (float*)d_ws;                       // N*64 f32 (final layer out)
  bf16*  x0b    = (bf16*)(B0f + (size_t)N_NODES * 64);          // N*16 bf16
  bf16*  B0b    = (bf16*)((float*)x0b + (size_t)N_NODES * 8);   // N*64 bf16
  bf16*  B1b    = (bf16*)((float*)B0b + (size_t)N_NODES * 32);  // N*64 bf16
  float* inv    = (float*)B1b + (size_t)N_NODES * 32; // N
  float* pooled = inv + N_NODES;                      // 250*64
  float* cnt    = pooled + (size_t)N_GRAPHS * 64;     // 250 (pad 256)
  int*   rowptr  = (int*)(cnt + 256);                 // N+1 (pad 100004)
  int*   esorted = rowptr + 100004;                   // E
  int*   gcnt    = esorted + N_EDGES;                 // NB (pad 400)
  int*   bbase   = gcnt + 400;                        // NB (pad 400)
  int*   binned  = (int*)B1b;                         // NB*BCAP ints (9.6MB <= B1b's 12.8MB;
                                                      // consumed by sort before L1 writes B1b)

  hipMemsetAsync(gcnt, 0, NB * sizeof(int), stream);
  hipMemsetAsync(pooled, 0, (N_GRAPHS * 64 + N_GRAPHS) * sizeof(float), stream);

  // CSR build: 2-level counting sort
  bin_kernel<<<BIN_BLOCKS, 256, 0, stream>>>(src, dst, gcnt, binned);
  bucketscan_kernel<<<1, 512, 0, stream>>>(gcnt, bbase, rowptr);
  sort_kernel<<<NB, 256, 0, stream>>>(gcnt, bbase, binned, esorted, rowptr, inv);

  // x0 bf16
  concat_kernel<<<(N_NODES * 16 + 255) / 256, 256, 0, stream>>>(nh, xg, batch, x0b);

  // fused layers: x0b -> B0b -> B1b -> B0f
  sage16_kernel<<<1024, 512, 0, stream>>>(x0b, rowptr, esorted, inv,
                                          s0Wl, s0bl, s0Wr, 13, B0b);
  sage64_kernel<true, false><<<512, 1024, 0, stream>>>(B0b, rowptr, esorted, inv,
                                                       s1Wl, s1bl, s1Wr, nullptr, B1b);
  sage64_kernel<false, true><<<512, 1024, 0, stream>>>(B1b, rowptr, esorted, inv,
                                                       s2Wl, s2bl, s2Wr, B0f, nullptr);

  // pooling + MLP
  pool_kernel<<<((N_NODES + 63) / 64 * 64 + 255) / 256, 256, 0, stream>>>(B0f, batch, pooled, cnt);
  mlp_kernel<<<N_GRAPHS, 64, 0, stream>>>(pooled, cnt, mW0, mb0, mW1, mb1, mW2, mb2, mW3, mb3,
                                          (float*)d_out);
}